// Round 7
// baseline (388.092 us; speedup 1.0000x reference)
//
#include <hip/hip_runtime.h>
#include <hip/hip_bf16.h>

typedef unsigned short u16;
typedef unsigned int   u32;
typedef float f32x2 __attribute__((ext_vector_type(2)));

static constexpr int NN = 100000;   // nodes
static constexpr int NE = 1600000;  // edges
static constexpr int NG = 64;       // graphs

static constexpr int BSH   = 8;     // nodes per bucket = 256
static constexpr int NBUCK = 391;   // ceil(NN / 256)
static constexpr int BCAP  = 5120;  // bucket capacity (mean 4096, sd ~64)
static constexpr int PB    = 8;     // pooling partial-blocks per graph
static constexpr int NB_G1 = (NN + 63) / 64;   // 1563 gemm1 blocks

// RTNE f32->bf16 pair pack
__device__ __forceinline__ u32 bf16pair(float a, float b) {
  u32 ua = __builtin_bit_cast(u32, a), ub = __builtin_bit_cast(u32, b);
  ua = (ua + 0x7FFFu + ((ua >> 16) & 1u)) >> 16;
  ub = (ub + 0x7FFFu + ((ub >> 16) & 1u)) >> 16;
  return ua | (ub << 16);
}
__device__ __forceinline__ float bflo(u32 u) { return __builtin_bit_cast(float, u << 16); }
__device__ __forceinline__ float bfhi(u32 u) { return __builtin_bit_cast(float, u & 0xFFFF0000u); }

// packed dual-FMA: a.lo += w.lo*bflo(u); a.hi += w.hi*bfhi(u)
__device__ __forceinline__ void pkfma(f32x2& a, f32x2 w2, u32 u) {
  f32x2 v;
  v.x = bflo(u); v.y = bfhi(u);
  asm("v_pk_fma_f32 %0, %1, %2, %0" : "+v"(a) : "v"(w2), "v"(v));
}

// ================= k_front: bin(0..390) | gemm1(391..1953) | gbounds(1954) =================
__global__ __launch_bounds__(256) void k_front(
    const float* __restrict__ x, const float* __restrict__ W1, const float* __restrict__ a1,
    const int* __restrict__ esrc, const int* __restrict__ edst, const int* __restrict__ batch,
    u16* __restrict__ Wh1b, float* __restrict__ es1, float* __restrict__ ed1,
    int* __restrict__ cur, u32* __restrict__ ebuf, int* __restrict__ gstart)
{
  __shared__ union U {
    struct { float xs[64][36]; float ws[32][128]; } g;
    struct { int lcnt[512]; int goff[NBUCK]; u32 bin[4096]; } b;
  } sm;
  const int bid = blockIdx.x;
  const int t = threadIdx.x;

  if (bid < NBUCK) {
    // ---------------- bin pass ----------------
    const int e0 = bid * 4096;
    sm.b.lcnt[t] = 0; sm.b.lcnt[t + 256] = 0;
    __syncthreads();
    u32 ent[16]; short bb[16], lp[16];
#pragma unroll
    for (int i = 0; i < 16; ++i) {
      int e = e0 + i * 256 + t;
      if (e < NE) {
        int s = esrc[e], d = edst[e];
        int b = d >> BSH;
        ent[i] = (u32)s | ((u32)(d & 255) << 20);
        bb[i] = (short)b;
        lp[i] = (short)atomicAdd(&sm.b.lcnt[b], 1);
      } else bb[i] = -1;
    }
    __syncthreads();
    for (int d = 1; d < 512; d <<= 1) {
      int v0 = (t >= d) ? sm.b.lcnt[t - d] : 0;
      int v1 = (t + 256 >= d) ? sm.b.lcnt[t + 256 - d] : 0;
      __syncthreads();
      sm.b.lcnt[t] += v0; sm.b.lcnt[t + 256] += v1;
      __syncthreads();
    }
    for (int b = t; b < NBUCK; b += 256) {
      int excl = b ? sm.b.lcnt[b - 1] : 0;
      int cnt = sm.b.lcnt[b] - excl;
      if (cnt) sm.b.goff[b] = b * BCAP + atomicAdd(&cur[b], cnt);
    }
#pragma unroll
    for (int i = 0; i < 16; ++i) {
      if (bb[i] >= 0) {
        int excl = bb[i] ? sm.b.lcnt[bb[i] - 1] : 0;
        sm.b.bin[excl + lp[i]] = ent[i];
      }
    }
    __syncthreads();
    const int total = sm.b.lcnt[NBUCK - 1];
    for (int i = t; i < total; i += 256) {
      int lo = 0, hi = NBUCK - 1;
      while (lo < hi) { int mid = (lo + hi) >> 1; if (sm.b.lcnt[mid] > i) hi = mid; else lo = mid + 1; }
      int excl = lo ? sm.b.lcnt[lo - 1] : 0;
      int g = sm.b.goff[lo] + (i - excl);
      if (g < (lo + 1) * BCAP) ebuf[g] = sm.b.bin[i];
    }
    return;
  }

  if (bid == NBUCK + NB_G1) {
    // ---------------- gbounds ----------------
    int g = t;
    if (g <= NG) {
      int lo = 0, hi = NN;
      while (lo < hi) { int mid = (lo + hi) >> 1; if (batch[mid] < g) lo = mid + 1; else hi = mid; }
      gstart[g] = lo;
    }
    return;
  }

  // ---------------- gemm1 ----------------
  const int rowBase = (bid - NBUCK) * 64;
  const int r0 = (t >> 4) * 4;
  const int c0 = (t & 15) * 8;
  float acc[4][8];
#pragma unroll
  for (int r = 0; r < 4; ++r)
#pragma unroll
    for (int c = 0; c < 8; ++c) acc[r][c] = 0.f;

  for (int k0 = 0; k0 < 128; k0 += 32) {
#pragma unroll
    for (int p = 0; p < 2; ++p) {
      int rr = (t >> 3) + p * 32;
      int cc = (t & 7) * 4;
      int grow = rowBase + rr;
      float4 v = make_float4(0.f, 0.f, 0.f, 0.f);
      if (grow < NN) v = *(const float4*)(&x[(size_t)grow * 128 + k0 + cc]);
      *(float4*)(&sm.g.xs[rr][cc]) = v;
    }
#pragma unroll
    for (int p = 0; p < 4; ++p) {
      int idx = (p * 256 + t) * 4;
      int kk = idx >> 7, cc = idx & 127;
      *(float4*)(&sm.g.ws[kk][cc]) = *(const float4*)(&W1[(size_t)(k0 + kk) * 128 + cc]);
    }
    __syncthreads();
#pragma unroll
    for (int k = 0; k < 32; ++k) {
      float a[4], b[8];
#pragma unroll
      for (int r = 0; r < 4; ++r) a[r] = sm.g.xs[r0 + r][k];
      *(float4*)&b[0] = *(float4*)&sm.g.ws[k][c0];
      *(float4*)&b[4] = *(float4*)&sm.g.ws[k][c0 + 4];
#pragma unroll
      for (int r = 0; r < 4; ++r)
#pragma unroll
        for (int c = 0; c < 8; ++c) acc[r][c] = fmaf(a[r], b[c], acc[r][c]);
    }
    __syncthreads();
  }
  const int h = (t & 15) >> 1;
  const int dbase = (t & 1) * 8;
  float a1s[8], a1d[8];
#pragma unroll
  for (int j = 0; j < 8; ++j) {
    a1s[j] = a1[h * 32 + dbase + j];
    a1d[j] = a1[h * 32 + 16 + dbase + j];
  }
#pragma unroll
  for (int r = 0; r < 4; ++r) {
    int grow = rowBase + r0 + r;
    float pes = 0.f, ped = 0.f;
#pragma unroll
    for (int j = 0; j < 8; ++j) {
      pes = fmaf(acc[r][j], a1s[j], pes);
      ped = fmaf(acc[r][j], a1d[j], ped);
    }
    pes += __shfl_xor(pes, 1);
    ped += __shfl_xor(ped, 1);
    if (grow < NN) {
      u32 p0 = bf16pair(acc[r][0], acc[r][1]);
      u32 p1 = bf16pair(acc[r][2], acc[r][3]);
      u32 p2 = bf16pair(acc[r][4], acc[r][5]);
      u32 p3 = bf16pair(acc[r][6], acc[r][7]);
      *(uint4*)(Wh1b + (size_t)grow * 128 + c0) = make_uint4(p0, p1, p2, p3);
      if ((t & 1) == 0) { es1[grow * 8 + h] = pes; ed1[grow * 8 + h] = ped; }
    }
  }
}

// ---------------- Pass C: per-bucket local counting sort ----------------
__global__ __launch_bounds__(256) void k_sort(
    const int* __restrict__ cur, u32* __restrict__ ebuf,
    int* __restrict__ offs, int* __restrict__ deg)
{
  __shared__ u32 ein[BCAP];
  __shared__ u32 eout[BCAP];
  __shared__ int nd[256];
  __shared__ int ncur[256];
  const int t = threadIdx.x;
  const int b = blockIdx.x;
  const int base = b * BCAP;
  int cnt = cur[b];
  if (cnt > BCAP) cnt = BCAP;
  const int nloc = min(256, NN - (b << BSH));

  for (int i = t; i < cnt; i += 256) ein[i] = ebuf[base + i];
  nd[t] = 0;
  __syncthreads();
  for (int i = t; i < cnt; i += 256) atomicAdd(&nd[ein[i] >> 20], 1);
  __syncthreads();
  const int myCnt = nd[t];
  for (int d = 1; d < 256; d <<= 1) {
    int v = (t >= d) ? nd[t - d] : 0;
    __syncthreads();
    nd[t] += v;
    __syncthreads();
  }
  const int excl = t ? nd[t - 1] : 0;
  ncur[t] = excl;
  if (t < nloc) {
    int node = (b << BSH) + t;
    offs[node] = base + excl;
    deg[node]  = myCnt;
  }
  __syncthreads();
  for (int i = t; i < cnt; i += 256) {
    u32 v = ein[i];
    int pos = atomicAdd(&ncur[v >> 20], 1);
    eout[pos] = v & 0xFFFFFu;
  }
  __syncthreads();
  for (int i = t; i < cnt; i += 256) ebuf[base + i] = eout[i];
}

// ---------------- Layer-1 aggregation: shuffle-free, pk_fma, h1 out in bf16 ----------------
__global__ __launch_bounds__(256) void k_agg1(
    const u16* __restrict__ Wh1b, const float* __restrict__ es1, const float* __restrict__ ed1,
    const int* __restrict__ offs, const int* __restrict__ deg, const int* __restrict__ csr,
    u16* __restrict__ h1b)
{
  const int wid = threadIdx.x >> 6;
  const int lane = threadIdx.x & 63;
  const int n = blockIdx.x * 4 + wid;
  if (n >= NN) return;
  const int s0 = offs[n];
  const int nE = deg[n];
  const int g = lane >> 4;        // edge group 0..3
  const int db = lane & 15;       // dim block
  const int h = db >> 1;          // head
  const float edv = ed1[n * 8 + h];

  f32x2 acc[4];
#pragma unroll
  for (int i = 0; i < 4; ++i) { acc[i].x = 0.f; acc[i].y = 0.f; }
  float ssum = 0.f;

  for (int c0 = 0; c0 < nE; c0 += 8) {
    const int j0 = c0 + g;
    const int j1 = c0 + 4 + g;
    const int sA = csr[s0 + (j0 < nE ? j0 : 0)];
    const int sB = csr[s0 + (j1 < nE ? j1 : 0)];
    float zA = es1[sA * 8 + h] + edv;
    float zB = es1[sB * 8 + h] + edv;
    zA = (zA > 0.f) ? zA : 0.2f * zA;
    zB = (zB > 0.f) ? zB : 0.2f * zB;
    if (j0 < nE) {
      const uint4 raw = *(const uint4*)(Wh1b + (size_t)sA * 128 + db * 8);
      const float w = __expf(zA);
      ssum += w;
      f32x2 w2; w2.x = w; w2.y = w;
      pkfma(acc[0], w2, raw.x);
      pkfma(acc[1], w2, raw.y);
      pkfma(acc[2], w2, raw.z);
      pkfma(acc[3], w2, raw.w);
    }
    if (j1 < nE) {
      const uint4 raw = *(const uint4*)(Wh1b + (size_t)sB * 128 + db * 8);
      const float w = __expf(zB);
      ssum += w;
      f32x2 w2; w2.x = w; w2.y = w;
      pkfma(acc[0], w2, raw.x);
      pkfma(acc[1], w2, raw.y);
      pkfma(acc[2], w2, raw.z);
      pkfma(acc[3], w2, raw.w);
    }
  }
  // reduce across the 4 edge-groups (lanes db, db+16, db+32, db+48)
#pragma unroll
  for (int i = 0; i < 4; ++i) {
    acc[i].x += __shfl_xor(acc[i].x, 16);
    acc[i].y += __shfl_xor(acc[i].y, 16);
    acc[i].x += __shfl_xor(acc[i].x, 32);
    acc[i].y += __shfl_xor(acc[i].y, 32);
  }
  ssum += __shfl_xor(ssum, 16);
  ssum += __shfl_xor(ssum, 32);

  if (g == 0) {
    float inv = 1.f / (ssum + 1e-16f);
    float o[8];
#pragma unroll
    for (int i = 0; i < 4; ++i) {
      float v0 = acc[i].x * inv;
      float v1 = acc[i].y * inv;
      o[2 * i]     = (v0 > 0.f) ? v0 : expm1f(v0);
      o[2 * i + 1] = (v1 > 0.f) ? v1 : expm1f(v1);
    }
    u32 p0 = bf16pair(o[0], o[1]);
    u32 p1 = bf16pair(o[2], o[3]);
    u32 p2 = bf16pair(o[4], o[5]);
    u32 p3 = bf16pair(o[6], o[7]);
    *(uint4*)(h1b + (size_t)n * 128 + db * 8) = make_uint4(p0, p1, p2, p3);
  }
}

// ---------------- GEMM2: Wh2b(bf16, stride 48) = h1b(bf16) @ W2(128,40), fused es2/ed2 ----
__global__ __launch_bounds__(256) void k_gemm2(
    const u16* __restrict__ h1b, const float* __restrict__ W2,
    const float* __restrict__ a2,
    u16* __restrict__ Wh2b, float* __restrict__ es2, float* __restrict__ ed2)
{
  __shared__ float hs[128][36];
  __shared__ float w2s[32][40];
  const int t = threadIdx.x;
  const int rowBase = blockIdx.x * 128;
  const int cg = t & 3;        // col group: cols cg*10 + j
  const int rs = t >> 2;
  float acc[2][10];
#pragma unroll
  for (int r = 0; r < 2; ++r)
#pragma unroll
    for (int j = 0; j < 10; ++j) acc[r][j] = 0.f;

  for (int k0 = 0; k0 < 128; k0 += 32) {
#pragma unroll
    for (int p = 0; p < 2; ++p) {
      int idx = (p * 256 + t) * 8;
      int rr = idx >> 5, cc = idx & 31;
      int grow = rowBase + rr;
      uint4 hv = make_uint4(0u, 0u, 0u, 0u);
      if (grow < NN) hv = *(const uint4*)(h1b + (size_t)grow * 128 + k0 + cc);
      float2* dst = (float2*)&hs[rr][cc];
      dst[0] = make_float2(bflo(hv.x), bfhi(hv.x));
      dst[1] = make_float2(bflo(hv.y), bfhi(hv.y));
      dst[2] = make_float2(bflo(hv.z), bfhi(hv.z));
      dst[3] = make_float2(bflo(hv.w), bfhi(hv.w));
    }
#pragma unroll
    for (int p = 0; p < 5; ++p) {
      int idx = p * 256 + t;
      int kk = idx / 40, cc = idx % 40;
      w2s[kk][cc] = W2[(size_t)(k0 + kk) * 40 + cc];
    }
    __syncthreads();
#pragma unroll
    for (int k = 0; k < 32; ++k) {
      float a0 = hs[rs][k], a1v = hs[rs + 64][k];
#pragma unroll
      for (int j = 0; j < 10; ++j) {
        float b = w2s[k][cg * 10 + j];
        acc[0][j] = fmaf(a0, b, acc[0][j]);
        acc[1][j] = fmaf(a1v, b, acc[1][j]);
      }
    }
    __syncthreads();
  }
  float a2s[10], a2d[10];
#pragma unroll
  for (int j = 0; j < 10; ++j) {
    a2s[j] = a2[cg * 10 + j];
    a2d[j] = a2[40 + cg * 10 + j];
  }
#pragma unroll
  for (int rr = 0; rr < 2; ++rr) {
    int grow = rowBase + rs + rr * 64;
    float pes = 0.f, ped = 0.f;
#pragma unroll
    for (int j = 0; j < 10; ++j) {
      float v = acc[rr][j];
      pes = fmaf(v, a2s[j], pes);
      ped = fmaf(v, a2d[j], ped);
    }
    if (grow < NN) {
      u32* dst = (u32*)(Wh2b + (size_t)grow * 48 + cg * 10);
      dst[0] = bf16pair(acc[rr][0], acc[rr][1]);
      dst[1] = bf16pair(acc[rr][2], acc[rr][3]);
      dst[2] = bf16pair(acc[rr][4], acc[rr][5]);
      dst[3] = bf16pair(acc[rr][6], acc[rr][7]);
      dst[4] = bf16pair(acc[rr][8], acc[rr][9]);
    }
    pes += __shfl_xor(pes, 1); pes += __shfl_xor(pes, 2);
    ped += __shfl_xor(ped, 1); ped += __shfl_xor(ped, 2);
    if (cg == 0 && grow < NN) { es2[grow] = pes; ed2[grow] = ped; }
  }
}

// ---------------- Layer-2 aggregation: shuffle-free, pk_fma ----------------
__global__ __launch_bounds__(256) void k_agg2(
    const u16* __restrict__ Wh2b, const float* __restrict__ es2, const float* __restrict__ ed2,
    const int* __restrict__ offs, const int* __restrict__ deg, const int* __restrict__ csr,
    float* __restrict__ h2)
{
  __shared__ float red[4][64][9];
  const int wid = threadIdx.x >> 6;
  const int lane = threadIdx.x & 63;
  const int n = blockIdx.x * 4 + wid;
  if (n >= NN) return;
  const int s0 = offs[n];
  const int nE = deg[n];
  const float edv = ed2[n];
  const int e5 = lane / 5, r5 = lane - e5 * 5;   // edge-group 0..11, dim-slot 0..4 (lane<60)
  const bool act = lane < 60;

  f32x2 acc[4];
#pragma unroll
  for (int i = 0; i < 4; ++i) { acc[i].x = 0.f; acc[i].y = 0.f; }
  float ssum = 0.f;

  for (int c0 = 0; c0 < nE; c0 += 24) {
    const int j0 = c0 + e5;
    const int j1 = c0 + 12 + e5;
    const int sA = csr[s0 + (j0 < nE ? j0 : 0)];
    const int sB = csr[s0 + (j1 < nE ? j1 : 0)];
    float zA = es2[sA] + edv;
    float zB = es2[sB] + edv;
    zA = (zA > 0.f) ? zA : 0.2f * zA;
    zB = (zB > 0.f) ? zB : 0.2f * zB;
    if (act && j0 < nE) {
      const uint4 raw = *(const uint4*)(Wh2b + (size_t)sA * 48 + r5 * 8);
      const float w = __expf(zA);
      ssum += w;
      f32x2 w2; w2.x = w; w2.y = w;
      pkfma(acc[0], w2, raw.x);
      pkfma(acc[1], w2, raw.y);
      pkfma(acc[2], w2, raw.z);
      pkfma(acc[3], w2, raw.w);
    }
    if (act && j1 < nE) {
      const uint4 raw = *(const uint4*)(Wh2b + (size_t)sB * 48 + r5 * 8);
      const float w = __expf(zB);
      ssum += w;
      f32x2 w2; w2.x = w; w2.y = w;
      pkfma(acc[0], w2, raw.x);
      pkfma(acc[1], w2, raw.y);
      pkfma(acc[2], w2, raw.z);
      pkfma(acc[3], w2, raw.w);
    }
  }
#pragma unroll
  for (int i = 0; i < 4; ++i) {
    red[wid][lane][2 * i]     = acc[i].x;
    red[wid][lane][2 * i + 1] = acc[i].y;
  }
  red[wid][lane][8] = ssum;
  __builtin_amdgcn_wave_barrier();
  if (lane < 40) {
    int slot = lane >> 3, i = lane & 7;
    float a = 0.f, sm = 0.f;
#pragma unroll
    for (int g = 0; g < 12; ++g) {
      a  += red[wid][g * 5 + slot][i];
      sm += red[wid][g * 5][8];
    }
    h2[(size_t)n * 40 + lane] = a / (sm + 1e-16f);
  }
}

// ---------------- Pooling ----------------
__global__ __launch_bounds__(256) void k_pool1(
    const float* __restrict__ h2, const int* __restrict__ gstart,
    float* __restrict__ partial)
{
  __shared__ float lds[25][10][4];
  const int g = blockIdx.x >> 3;
  const int p = blockIdx.x & 7;
  const int t = threadIdx.x;
  const int s0 = gstart[g], s1 = gstart[g + 1];
  const int len = s1 - s0;
  const int chunk = (len + PB - 1) / PB;
  const int start = s0 + p * chunk;
  const int end = min(start + chunk, s1);
  const int slot = t / 10, q = t - slot * 10;
  float4 acc = make_float4(0.f, 0.f, 0.f, 0.f);
  if (slot < 25) {
    for (int n = start + slot; n < end; n += 25) {
      const float4 v = *(const float4*)(&h2[(size_t)n * 40 + q * 4]);
      acc.x += v.x; acc.y += v.y; acc.z += v.z; acc.w += v.w;
    }
    lds[slot][q][0] = acc.x; lds[slot][q][1] = acc.y;
    lds[slot][q][2] = acc.z; lds[slot][q][3] = acc.w;
  }
  __syncthreads();
  if (t < 40) {
    const int qq = t >> 2, e = t & 3;
    float s = 0.f;
#pragma unroll
    for (int sl = 0; sl < 25; ++sl) s += lds[sl][qq][e];
    partial[(size_t)blockIdx.x * 40 + t] = s;
  }
}

__global__ void k_pool2(const float* __restrict__ partial, const int* __restrict__ gstart,
                        float* __restrict__ out)
{
  const int g = blockIdx.x;
  const int d = threadIdx.x;
  if (d >= 40) return;
  float s = 0.f;
#pragma unroll
  for (int p = 0; p < PB; ++p) s += partial[(size_t)(g * PB + p) * 40 + d];
  int cnt = gstart[g + 1] - gstart[g];
  if (cnt < 1) cnt = 1;
  out[g * 40 + d] = s / (float)cnt;
}

extern "C" void kernel_launch(void* const* d_in, const int* in_sizes, int n_in,
                              void* d_out, int out_size, void* d_ws, size_t ws_size,
                              hipStream_t stream)
{
  const float* x   = (const float*)d_in[0];
  const float* W1  = (const float*)d_in[1];
  const float* a1  = (const float*)d_in[2];
  const float* W2  = (const float*)d_in[3];
  const float* a2  = (const float*)d_in[4];
  const int* eidx  = (const int*)d_in[5];
  const int* batch = (const int*)d_in[6];
  float* out = (float*)d_out;

  char* ws = (char*)d_ws;
  u16*   Wh1b = (u16*)(ws + 0);              // 25,600,000 B
  u16*   Wh2b = (u16*)(ws + 0);              //  9,600,000 B (reuse after agg1)
  float* h2   = (float*)(ws + 9600000);      // 16,000,000 B (reuse)
  u16*   h1b  = (u16*)(ws + 25600000);       // 25,600,000 B
  float* es1  = (float*)(ws + 51200000);     //  3,200,000
  float* ed1  = (float*)(ws + 54400000);     //  3,200,000
  float* es2  = (float*)(ws + 57600000);     //    400,000
  float* ed2  = (float*)(ws + 58000000);     //    400,000
  u32*   ebuf = (u32*)(ws + 58400000);       //  8,007,680 (NBUCK*BCAP*4) -> becomes csr
  int*   offs = (int*)(ws + 66407680);       //    400,000
  int*   deg  = (int*)(ws + 66807680);       //    400,000
  int*   cur  = (int*)(ws + 67207680);       //      2,048
  int*   gstart = (int*)(ws + 67209728);     //        512
  float* partial = (float*)(ws + 67210240);  //     81,920 (NG*PB*40*4)
  // total ~67.3 MB

  const int* esrc = eidx;
  const int* edst = eidx + NE;

  hipMemsetAsync(cur, 0, NBUCK * sizeof(int), stream);
  k_front<<<NBUCK + NB_G1 + 1, 256, 0, stream>>>(x, W1, a1, esrc, edst, batch,
                                                 Wh1b, es1, ed1, cur, ebuf, gstart);
  k_sort<<<NBUCK, 256, 0, stream>>>(cur, ebuf, offs, deg);
  k_agg1<<<(NN + 3) / 4, 256, 0, stream>>>(Wh1b, es1, ed1, offs, deg, (const int*)ebuf, h1b);
  k_gemm2<<<(NN + 127) / 128, 256, 0, stream>>>(h1b, W2, a2, Wh2b, es2, ed2);
  k_agg2<<<(NN + 3) / 4, 256, 0, stream>>>(Wh2b, es2, ed2, offs, deg, (const int*)ebuf, h2);
  k_pool1<<<NG * PB, 256, 0, stream>>>(h2, gstart, partial);
  k_pool2<<<NG, 64, 0, stream>>>(partial, gstart, out);
}

// Round 8
// 286.298 us; speedup vs baseline: 1.3556x; 1.3556x over previous
//
#include <hip/hip_runtime.h>
#include <hip/hip_bf16.h>

typedef unsigned short u16;
typedef unsigned int   u32;
typedef float f32x2 __attribute__((ext_vector_type(2)));

static constexpr int NN = 100000;   // nodes
static constexpr int NE = 1600000;  // edges
static constexpr int NG = 64;       // graphs

static constexpr int BSH   = 8;     // nodes per bucket = 256
static constexpr int NBUCK = 391;   // ceil(NN / 256)
static constexpr int BCAP  = 5120;  // bucket capacity (mean 4096, sd ~64)
static constexpr int PB    = 8;     // pooling partial-blocks per graph

// RTNE f32->bf16 pair pack
__device__ __forceinline__ u32 bf16pair(float a, float b) {
  u32 ua = __builtin_bit_cast(u32, a), ub = __builtin_bit_cast(u32, b);
  ua = (ua + 0x7FFFu + ((ua >> 16) & 1u)) >> 16;
  ub = (ub + 0x7FFFu + ((ub >> 16) & 1u)) >> 16;
  return ua | (ub << 16);
}
__device__ __forceinline__ float bflo(u32 u) { return __builtin_bit_cast(float, u << 16); }
__device__ __forceinline__ float bfhi(u32 u) { return __builtin_bit_cast(float, u & 0xFFFF0000u); }

// packed dual-FMA: a.lo += w.lo*bflo(u); a.hi += w.hi*bfhi(u)
__device__ __forceinline__ void pkfma(f32x2& a, f32x2 w2, u32 u) {
  f32x2 v;
  v.x = bflo(u); v.y = bfhi(u);
  asm("v_pk_fma_f32 %0, %1, %2, %0" : "+v"(a) : "v"(w2), "v"(v));
}

// ---------------- GEMM1: Wh1b(bf16) = x(N,128) @ W1(128,128), fused es1/ed1 ----------------
__global__ __launch_bounds__(256) void k_gemm1(
    const float* __restrict__ x, const float* __restrict__ W1,
    const float* __restrict__ a1,
    u16* __restrict__ Wh1b, float* __restrict__ es1, float* __restrict__ ed1)
{
  __shared__ float xs[64][36];
  __shared__ float ws[32][128];
  const int t = threadIdx.x;
  const int rowBase = blockIdx.x * 64;
  const int r0 = (t >> 4) * 4;
  const int c0 = (t & 15) * 8;
  float acc[4][8];
#pragma unroll
  for (int r = 0; r < 4; ++r)
#pragma unroll
    for (int c = 0; c < 8; ++c) acc[r][c] = 0.f;

  for (int k0 = 0; k0 < 128; k0 += 32) {
#pragma unroll
    for (int p = 0; p < 2; ++p) {
      int rr = (t >> 3) + p * 32;
      int cc = (t & 7) * 4;
      int grow = rowBase + rr;
      float4 v = make_float4(0.f, 0.f, 0.f, 0.f);
      if (grow < NN) v = *(const float4*)(&x[(size_t)grow * 128 + k0 + cc]);
      *(float4*)(&xs[rr][cc]) = v;
    }
#pragma unroll
    for (int p = 0; p < 4; ++p) {
      int idx = (p * 256 + t) * 4;
      int kk = idx >> 7, cc = idx & 127;
      *(float4*)(&ws[kk][cc]) = *(const float4*)(&W1[(size_t)(k0 + kk) * 128 + cc]);
    }
    __syncthreads();
#pragma unroll
    for (int k = 0; k < 32; ++k) {
      float a[4], b[8];
#pragma unroll
      for (int r = 0; r < 4; ++r) a[r] = xs[r0 + r][k];
      *(float4*)&b[0] = *(float4*)&ws[k][c0];
      *(float4*)&b[4] = *(float4*)&ws[k][c0 + 4];
#pragma unroll
      for (int r = 0; r < 4; ++r)
#pragma unroll
        for (int c = 0; c < 8; ++c) acc[r][c] = fmaf(a[r], b[c], acc[r][c]);
    }
    __syncthreads();
  }
  const int h = (t & 15) >> 1;
  const int dbase = (t & 1) * 8;
  float a1s[8], a1d[8];
#pragma unroll
  for (int j = 0; j < 8; ++j) {
    a1s[j] = a1[h * 32 + dbase + j];
    a1d[j] = a1[h * 32 + 16 + dbase + j];
  }
#pragma unroll
  for (int r = 0; r < 4; ++r) {
    int grow = rowBase + r0 + r;
    float pes = 0.f, ped = 0.f;
#pragma unroll
    for (int j = 0; j < 8; ++j) {
      pes = fmaf(acc[r][j], a1s[j], pes);
      ped = fmaf(acc[r][j], a1d[j], ped);
    }
    pes += __shfl_xor(pes, 1);
    ped += __shfl_xor(ped, 1);
    if (grow < NN) {
      u32 p0 = bf16pair(acc[r][0], acc[r][1]);
      u32 p1 = bf16pair(acc[r][2], acc[r][3]);
      u32 p2 = bf16pair(acc[r][4], acc[r][5]);
      u32 p3 = bf16pair(acc[r][6], acc[r][7]);
      *(uint4*)(Wh1b + (size_t)grow * 128 + c0) = make_uint4(p0, p1, p2, p3);
      if ((t & 1) == 0) { es1[grow * 8 + h] = pes; ed1[grow * 8 + h] = ped; }
    }
  }
}

// ---------------- Pass B: LDS-staged binning (standalone, low-VGPR, high occupancy) --------
__global__ __launch_bounds__(256) void k_bin(
    const int* __restrict__ src, const int* __restrict__ dst,
    int* __restrict__ cur, u32* __restrict__ ebuf)
{
  __shared__ int lcnt[512];
  __shared__ int goff[NBUCK];
  __shared__ u32 bin[4096];
  const int t = threadIdx.x;
  const int e0 = blockIdx.x * 4096;

  lcnt[t] = 0; lcnt[t + 256] = 0;
  __syncthreads();

  u32 ent[16]; short bb[16], lp[16];
#pragma unroll
  for (int i = 0; i < 16; ++i) {
    int e = e0 + i * 256 + t;
    if (e < NE) {
      int s = src[e], d = dst[e];
      int b = d >> BSH;
      ent[i] = (u32)s | ((u32)(d & 255) << 20);
      bb[i] = (short)b;
      lp[i] = (short)atomicAdd(&lcnt[b], 1);
    } else bb[i] = -1;
  }
  __syncthreads();
  for (int d = 1; d < 512; d <<= 1) {
    int v0 = (t >= d) ? lcnt[t - d] : 0;
    int v1 = (t + 256 >= d) ? lcnt[t + 256 - d] : 0;
    __syncthreads();
    lcnt[t] += v0; lcnt[t + 256] += v1;
    __syncthreads();
  }
  for (int b = t; b < NBUCK; b += 256) {
    int excl = b ? lcnt[b - 1] : 0;
    int cnt = lcnt[b] - excl;
    if (cnt) goff[b] = b * BCAP + atomicAdd(&cur[b], cnt);
  }
#pragma unroll
  for (int i = 0; i < 16; ++i) {
    if (bb[i] >= 0) {
      int excl = bb[i] ? lcnt[bb[i] - 1] : 0;
      bin[excl + lp[i]] = ent[i];
    }
  }
  __syncthreads();
  const int total = lcnt[NBUCK - 1];
  for (int i = t; i < total; i += 256) {
    int lo = 0, hi = NBUCK - 1;
    while (lo < hi) { int mid = (lo + hi) >> 1; if (lcnt[mid] > i) hi = mid; else lo = mid + 1; }
    int excl = lo ? lcnt[lo - 1] : 0;
    int g = goff[lo] + (i - excl);
    if (g < (lo + 1) * BCAP) ebuf[g] = bin[i];
  }
}

// ---------------- Pass C: per-bucket local counting sort ----------------
__global__ __launch_bounds__(256) void k_sort(
    const int* __restrict__ cur, u32* __restrict__ ebuf,
    int* __restrict__ offs, int* __restrict__ deg)
{
  __shared__ u32 ein[BCAP];
  __shared__ u32 eout[BCAP];
  __shared__ int nd[256];
  __shared__ int ncur[256];
  const int t = threadIdx.x;
  const int b = blockIdx.x;
  const int base = b * BCAP;
  int cnt = cur[b];
  if (cnt > BCAP) cnt = BCAP;
  const int nloc = min(256, NN - (b << BSH));

  for (int i = t; i < cnt; i += 256) ein[i] = ebuf[base + i];
  nd[t] = 0;
  __syncthreads();
  for (int i = t; i < cnt; i += 256) atomicAdd(&nd[ein[i] >> 20], 1);
  __syncthreads();
  const int myCnt = nd[t];
  for (int d = 1; d < 256; d <<= 1) {
    int v = (t >= d) ? nd[t - d] : 0;
    __syncthreads();
    nd[t] += v;
    __syncthreads();
  }
  const int excl = t ? nd[t - 1] : 0;
  ncur[t] = excl;
  if (t < nloc) {
    int node = (b << BSH) + t;
    offs[node] = base + excl;
    deg[node]  = myCnt;
  }
  __syncthreads();
  for (int i = t; i < cnt; i += 256) {
    u32 v = ein[i];
    int pos = atomicAdd(&ncur[v >> 20], 1);
    eout[pos] = v & 0xFFFFFu;
  }
  __syncthreads();
  for (int i = t; i < cnt; i += 256) ebuf[base + i] = eout[i];
}

// ---------------- Layer-1 aggregation: shuffle-free, pk_fma, h1 out in bf16 ----------------
__global__ __launch_bounds__(256) void k_agg1(
    const u16* __restrict__ Wh1b, const float* __restrict__ es1, const float* __restrict__ ed1,
    const int* __restrict__ offs, const int* __restrict__ deg, const int* __restrict__ csr,
    u16* __restrict__ h1b)
{
  const int wid = threadIdx.x >> 6;
  const int lane = threadIdx.x & 63;
  const int n = blockIdx.x * 4 + wid;
  if (n >= NN) return;
  const int s0 = offs[n];
  const int nE = deg[n];
  const int g = lane >> 4;        // edge group 0..3
  const int db = lane & 15;       // dim block
  const int h = db >> 1;          // head
  const float edv = ed1[n * 8 + h];

  f32x2 acc[4];
#pragma unroll
  for (int i = 0; i < 4; ++i) { acc[i].x = 0.f; acc[i].y = 0.f; }
  float ssum = 0.f;

  for (int c0 = 0; c0 < nE; c0 += 8) {
    const int j0 = c0 + g;
    const int j1 = c0 + 4 + g;
    const int sA = csr[s0 + (j0 < nE ? j0 : 0)];
    const int sB = csr[s0 + (j1 < nE ? j1 : 0)];
    float zA = es1[sA * 8 + h] + edv;
    float zB = es1[sB * 8 + h] + edv;
    zA = (zA > 0.f) ? zA : 0.2f * zA;
    zB = (zB > 0.f) ? zB : 0.2f * zB;
    if (j0 < nE) {
      const uint4 raw = *(const uint4*)(Wh1b + (size_t)sA * 128 + db * 8);
      const float w = __expf(zA);
      ssum += w;
      f32x2 w2; w2.x = w; w2.y = w;
      pkfma(acc[0], w2, raw.x);
      pkfma(acc[1], w2, raw.y);
      pkfma(acc[2], w2, raw.z);
      pkfma(acc[3], w2, raw.w);
    }
    if (j1 < nE) {
      const uint4 raw = *(const uint4*)(Wh1b + (size_t)sB * 128 + db * 8);
      const float w = __expf(zB);
      ssum += w;
      f32x2 w2; w2.x = w; w2.y = w;
      pkfma(acc[0], w2, raw.x);
      pkfma(acc[1], w2, raw.y);
      pkfma(acc[2], w2, raw.z);
      pkfma(acc[3], w2, raw.w);
    }
  }
#pragma unroll
  for (int i = 0; i < 4; ++i) {
    acc[i].x += __shfl_xor(acc[i].x, 16);
    acc[i].y += __shfl_xor(acc[i].y, 16);
    acc[i].x += __shfl_xor(acc[i].x, 32);
    acc[i].y += __shfl_xor(acc[i].y, 32);
  }
  ssum += __shfl_xor(ssum, 16);
  ssum += __shfl_xor(ssum, 32);

  if (g == 0) {
    float inv = 1.f / (ssum + 1e-16f);
    float o[8];
#pragma unroll
    for (int i = 0; i < 4; ++i) {
      float v0 = acc[i].x * inv;
      float v1 = acc[i].y * inv;
      o[2 * i]     = (v0 > 0.f) ? v0 : expm1f(v0);
      o[2 * i + 1] = (v1 > 0.f) ? v1 : expm1f(v1);
    }
    u32 p0 = bf16pair(o[0], o[1]);
    u32 p1 = bf16pair(o[2], o[3]);
    u32 p2 = bf16pair(o[4], o[5]);
    u32 p3 = bf16pair(o[6], o[7]);
    *(uint4*)(h1b + (size_t)n * 128 + db * 8) = make_uint4(p0, p1, p2, p3);
  }
}

// ---------------- GEMM2: Wh2b(bf16, stride 48) = h1b(bf16) @ W2(128,40), fused es2/ed2 ----
__global__ __launch_bounds__(256) void k_gemm2(
    const u16* __restrict__ h1b, const float* __restrict__ W2,
    const float* __restrict__ a2,
    u16* __restrict__ Wh2b, float* __restrict__ es2, float* __restrict__ ed2)
{
  __shared__ float hs[128][36];
  __shared__ float w2s[32][40];
  const int t = threadIdx.x;
  const int rowBase = blockIdx.x * 128;
  const int cg = t & 3;        // col group: cols cg*10 + j
  const int rs = t >> 2;
  float acc[2][10];
#pragma unroll
  for (int r = 0; r < 2; ++r)
#pragma unroll
    for (int j = 0; j < 10; ++j) acc[r][j] = 0.f;

  for (int k0 = 0; k0 < 128; k0 += 32) {
#pragma unroll
    for (int p = 0; p < 2; ++p) {
      int idx = (p * 256 + t) * 8;
      int rr = idx >> 5, cc = idx & 31;
      int grow = rowBase + rr;
      uint4 hv = make_uint4(0u, 0u, 0u, 0u);
      if (grow < NN) hv = *(const uint4*)(h1b + (size_t)grow * 128 + k0 + cc);
      float2* dst = (float2*)&hs[rr][cc];
      dst[0] = make_float2(bflo(hv.x), bfhi(hv.x));
      dst[1] = make_float2(bflo(hv.y), bfhi(hv.y));
      dst[2] = make_float2(bflo(hv.z), bfhi(hv.z));
      dst[3] = make_float2(bflo(hv.w), bfhi(hv.w));
    }
#pragma unroll
    for (int p = 0; p < 5; ++p) {
      int idx = p * 256 + t;
      int kk = idx / 40, cc = idx % 40;
      w2s[kk][cc] = W2[(size_t)(k0 + kk) * 40 + cc];
    }
    __syncthreads();
#pragma unroll
    for (int k = 0; k < 32; ++k) {
      float a0 = hs[rs][k], a1v = hs[rs + 64][k];
#pragma unroll
      for (int j = 0; j < 10; ++j) {
        float b = w2s[k][cg * 10 + j];
        acc[0][j] = fmaf(a0, b, acc[0][j]);
        acc[1][j] = fmaf(a1v, b, acc[1][j]);
      }
    }
    __syncthreads();
  }
  float a2s[10], a2d[10];
#pragma unroll
  for (int j = 0; j < 10; ++j) {
    a2s[j] = a2[cg * 10 + j];
    a2d[j] = a2[40 + cg * 10 + j];
  }
#pragma unroll
  for (int rr = 0; rr < 2; ++rr) {
    int grow = rowBase + rs + rr * 64;
    float pes = 0.f, ped = 0.f;
#pragma unroll
    for (int j = 0; j < 10; ++j) {
      float v = acc[rr][j];
      pes = fmaf(v, a2s[j], pes);
      ped = fmaf(v, a2d[j], ped);
    }
    if (grow < NN) {
      u32* dst = (u32*)(Wh2b + (size_t)grow * 48 + cg * 10);
      dst[0] = bf16pair(acc[rr][0], acc[rr][1]);
      dst[1] = bf16pair(acc[rr][2], acc[rr][3]);
      dst[2] = bf16pair(acc[rr][4], acc[rr][5]);
      dst[3] = bf16pair(acc[rr][6], acc[rr][7]);
      dst[4] = bf16pair(acc[rr][8], acc[rr][9]);
    }
    pes += __shfl_xor(pes, 1); pes += __shfl_xor(pes, 2);
    ped += __shfl_xor(ped, 1); ped += __shfl_xor(ped, 2);
    if (cg == 0 && grow < NN) { es2[grow] = pes; ed2[grow] = ped; }
  }
}

// ---------------- Layer-2 aggregation: shuffle-free, pk_fma ----------------
__global__ __launch_bounds__(256) void k_agg2(
    const u16* __restrict__ Wh2b, const float* __restrict__ es2, const float* __restrict__ ed2,
    const int* __restrict__ offs, const int* __restrict__ deg, const int* __restrict__ csr,
    float* __restrict__ h2)
{
  __shared__ float red[4][64][9];
  const int wid = threadIdx.x >> 6;
  const int lane = threadIdx.x & 63;
  const int n = blockIdx.x * 4 + wid;
  if (n >= NN) return;
  const int s0 = offs[n];
  const int nE = deg[n];
  const float edv = ed2[n];
  const int e5 = lane / 5, r5 = lane - e5 * 5;   // edge-group 0..11, dim-slot 0..4 (lane<60)
  const bool act = lane < 60;

  f32x2 acc[4];
#pragma unroll
  for (int i = 0; i < 4; ++i) { acc[i].x = 0.f; acc[i].y = 0.f; }
  float ssum = 0.f;

  for (int c0 = 0; c0 < nE; c0 += 24) {
    const int j0 = c0 + e5;
    const int j1 = c0 + 12 + e5;
    const int sA = csr[s0 + (j0 < nE ? j0 : 0)];
    const int sB = csr[s0 + (j1 < nE ? j1 : 0)];
    float zA = es2[sA] + edv;
    float zB = es2[sB] + edv;
    zA = (zA > 0.f) ? zA : 0.2f * zA;
    zB = (zB > 0.f) ? zB : 0.2f * zB;
    if (act && j0 < nE) {
      const uint4 raw = *(const uint4*)(Wh2b + (size_t)sA * 48 + r5 * 8);
      const float w = __expf(zA);
      ssum += w;
      f32x2 w2; w2.x = w; w2.y = w;
      pkfma(acc[0], w2, raw.x);
      pkfma(acc[1], w2, raw.y);
      pkfma(acc[2], w2, raw.z);
      pkfma(acc[3], w2, raw.w);
    }
    if (act && j1 < nE) {
      const uint4 raw = *(const uint4*)(Wh2b + (size_t)sB * 48 + r5 * 8);
      const float w = __expf(zB);
      ssum += w;
      f32x2 w2; w2.x = w; w2.y = w;
      pkfma(acc[0], w2, raw.x);
      pkfma(acc[1], w2, raw.y);
      pkfma(acc[2], w2, raw.z);
      pkfma(acc[3], w2, raw.w);
    }
  }
#pragma unroll
  for (int i = 0; i < 4; ++i) {
    red[wid][lane][2 * i]     = acc[i].x;
    red[wid][lane][2 * i + 1] = acc[i].y;
  }
  red[wid][lane][8] = ssum;
  __builtin_amdgcn_wave_barrier();
  if (lane < 40) {
    int slot = lane >> 3, i = lane & 7;
    float a = 0.f, sm = 0.f;
#pragma unroll
    for (int g = 0; g < 12; ++g) {
      a  += red[wid][g * 5 + slot][i];
      sm += red[wid][g * 5][8];
    }
    h2[(size_t)n * 40 + lane] = a / (sm + 1e-16f);
  }
}

// ---------------- Pooling ----------------
__global__ void k_gbounds(const int* __restrict__ batch, int* __restrict__ gstart) {
  int g = threadIdx.x;
  if (g > NG) return;
  int lo = 0, hi = NN;
  while (lo < hi) { int mid = (lo + hi) >> 1; if (batch[mid] < g) lo = mid + 1; else hi = mid; }
  gstart[g] = lo;
}

__global__ __launch_bounds__(256) void k_pool1(
    const float* __restrict__ h2, const int* __restrict__ gstart,
    float* __restrict__ partial)
{
  __shared__ float lds[25][10][4];
  const int g = blockIdx.x >> 3;
  const int p = blockIdx.x & 7;
  const int t = threadIdx.x;
  const int s0 = gstart[g], s1 = gstart[g + 1];
  const int len = s1 - s0;
  const int chunk = (len + PB - 1) / PB;
  const int start = s0 + p * chunk;
  const int end = min(start + chunk, s1);
  const int slot = t / 10, q = t - slot * 10;
  float4 acc = make_float4(0.f, 0.f, 0.f, 0.f);
  if (slot < 25) {
    for (int n = start + slot; n < end; n += 25) {
      const float4 v = *(const float4*)(&h2[(size_t)n * 40 + q * 4]);
      acc.x += v.x; acc.y += v.y; acc.z += v.z; acc.w += v.w;
    }
    lds[slot][q][0] = acc.x; lds[slot][q][1] = acc.y;
    lds[slot][q][2] = acc.z; lds[slot][q][3] = acc.w;
  }
  __syncthreads();
  if (t < 40) {
    const int qq = t >> 2, e = t & 3;
    float s = 0.f;
#pragma unroll
    for (int sl = 0; sl < 25; ++sl) s += lds[sl][qq][e];
    partial[(size_t)blockIdx.x * 40 + t] = s;
  }
}

__global__ void k_pool2(const float* __restrict__ partial, const int* __restrict__ gstart,
                        float* __restrict__ out)
{
  const int g = blockIdx.x;
  const int d = threadIdx.x;
  if (d >= 40) return;
  float s = 0.f;
#pragma unroll
  for (int p = 0; p < PB; ++p) s += partial[(size_t)(g * PB + p) * 40 + d];
  int cnt = gstart[g + 1] - gstart[g];
  if (cnt < 1) cnt = 1;
  out[g * 40 + d] = s / (float)cnt;
}

extern "C" void kernel_launch(void* const* d_in, const int* in_sizes, int n_in,
                              void* d_out, int out_size, void* d_ws, size_t ws_size,
                              hipStream_t stream)
{
  const float* x   = (const float*)d_in[0];
  const float* W1  = (const float*)d_in[1];
  const float* a1  = (const float*)d_in[2];
  const float* W2  = (const float*)d_in[3];
  const float* a2  = (const float*)d_in[4];
  const int* eidx  = (const int*)d_in[5];
  const int* batch = (const int*)d_in[6];
  float* out = (float*)d_out;

  char* ws = (char*)d_ws;
  u16*   Wh1b = (u16*)(ws + 0);              // 25,600,000 B
  u16*   Wh2b = (u16*)(ws + 0);              //  9,600,000 B (reuse after agg1)
  float* h2   = (float*)(ws + 9600000);      // 16,000,000 B (reuse)
  u16*   h1b  = (u16*)(ws + 25600000);       // 25,600,000 B
  float* es1  = (float*)(ws + 51200000);     //  3,200,000
  float* ed1  = (float*)(ws + 54400000);     //  3,200,000
  float* es2  = (float*)(ws + 57600000);     //    400,000
  float* ed2  = (float*)(ws + 58000000);     //    400,000
  u32*   ebuf = (u32*)(ws + 58400000);       //  8,007,680 (NBUCK*BCAP*4) -> becomes csr
  int*   offs = (int*)(ws + 66407680);       //    400,000
  int*   deg  = (int*)(ws + 66807680);       //    400,000
  int*   cur  = (int*)(ws + 67207680);       //      2,048
  int*   gstart = (int*)(ws + 67209728);     //        512
  float* partial = (float*)(ws + 67210240);  //     81,920 (NG*PB*40*4)
  // total ~67.3 MB

  const int* esrc = eidx;
  const int* edst = eidx + NE;

  hipMemsetAsync(cur, 0, NBUCK * sizeof(int), stream);
  k_gbounds<<<1, 128, 0, stream>>>(batch, gstart);
  k_gemm1<<<(NN + 63) / 64, 256, 0, stream>>>(x, W1, a1, Wh1b, es1, ed1);
  k_bin<<<(NE + 4095) / 4096, 256, 0, stream>>>(esrc, edst, cur, ebuf);
  k_sort<<<NBUCK, 256, 0, stream>>>(cur, ebuf, offs, deg);
  k_agg1<<<(NN + 3) / 4, 256, 0, stream>>>(Wh1b, es1, ed1, offs, deg, (const int*)ebuf, h1b);
  k_gemm2<<<(NN + 127) / 128, 256, 0, stream>>>(h1b, W2, a2, Wh2b, es2, ed2);
  k_agg2<<<(NN + 3) / 4, 256, 0, stream>>>(Wh2b, es2, ed2, offs, deg, (const int*)ebuf, h2);
  k_pool1<<<NG * PB, 256, 0, stream>>>(h2, gstart, partial);
  k_pool2<<<NG, 64, 0, stream>>>(partial, gstart, out);
}

// Round 9
// 266.904 us; speedup vs baseline: 1.4541x; 1.0727x over previous
//
#include <hip/hip_runtime.h>
#include <hip/hip_bf16.h>

typedef unsigned short u16;
typedef unsigned int   u32;
typedef float f32x2 __attribute__((ext_vector_type(2)));
typedef float f32x4 __attribute__((ext_vector_type(4)));
typedef short bf16x8 __attribute__((ext_vector_type(8)));

static constexpr int NN = 100000;   // nodes
static constexpr int NE = 1600000;  // edges
static constexpr int NG = 64;       // graphs

static constexpr int BSH   = 8;     // nodes per bucket = 256
static constexpr int NBUCK = 391;   // ceil(NN / 256)
static constexpr int BCAP  = 5120;  // bucket capacity (mean 4096, sd ~64)
static constexpr int PB    = 8;     // pooling partial-blocks per graph

// RTNE f32->bf16
__device__ __forceinline__ u16 bf16rte(float a) {
  u32 u = __builtin_bit_cast(u32, a);
  u = (u + 0x7FFFu + ((u >> 16) & 1u)) >> 16;
  return (u16)u;
}
__device__ __forceinline__ u32 bf16pair(float a, float b) {
  return (u32)bf16rte(a) | ((u32)bf16rte(b) << 16);
}
__device__ __forceinline__ float bflo(u32 u) { return __builtin_bit_cast(float, u << 16); }
__device__ __forceinline__ float bfhi(u32 u) { return __builtin_bit_cast(float, u & 0xFFFF0000u); }

// packed dual-FMA: a.lo += w.lo*bflo(u); a.hi += w.hi*bfhi(u)
__device__ __forceinline__ void pkfma(f32x2& a, f32x2 w2, u32 u) {
  f32x2 v;
  v.x = bflo(u); v.y = bfhi(u);
  asm("v_pk_fma_f32 %0, %1, %2, %0" : "+v"(a) : "v"(w2), "v"(v));
}

// ---------------- prep: W1 -> bf16, transposed [col][k], kg-swizzled, in global ----------
// layout: wsTg[c*128 + ((k>>3) ^ (c&7))*8 + (k&7)]
__global__ void k_prepW(const float* __restrict__ W1, u16* __restrict__ wsTg) {
  const int t = threadIdx.x;
  for (int rep = 0; rep < 64; ++rep) {
    int idx = rep * 256 + t;
    int k = idx >> 7, c = idx & 127;
    float v = W1[idx];
    wsTg[c * 128 + (((k >> 3) ^ (c & 7)) << 3) + (k & 7)] = bf16rte(v);
  }
}

// ---------------- GEMM1 (MFMA bf16): Wh1b = x @ W1, fused es1/ed1 ----------------
// block: 256 thr = 4 waves; tile 64 rows x 128 cols; wave w covers cols w*32..w*32+31.
__global__ __launch_bounds__(256) void k_gemm1(
    const float* __restrict__ x, const u16* __restrict__ wsTg, const float* __restrict__ a1,
    u16* __restrict__ Wh1b, float* __restrict__ es1, float* __restrict__ ed1)
{
  __shared__ u16 wsT[128][128];   // [col][k], kg' = kg ^ (col&7)  (32 KB)
  __shared__ u16 xsb[64][32];     // [row][k-in-step], kg' = kg ^ ((row>>1)&3)  (4 KB)
  const int t = threadIdx.x;
  const int w = t >> 6, l = t & 63;
  const int rowBase = blockIdx.x * 64;

  // stage swizzled W1^T (bf16) linearly: 32 KB, 128 B/thread
  {
    const uint4* src = (const uint4*)wsTg;
    uint4* dst = (uint4*)&wsT[0][0];
#pragma unroll
    for (int i = 0; i < 8; ++i) dst[t * 8 + i] = src[t * 8 + i];
  }

  f32x4 acc[4][2];
#pragma unroll
  for (int r = 0; r < 4; ++r)
#pragma unroll
    for (int cf = 0; cf < 2; ++cf) acc[r][cf] = (f32x4){0.f, 0.f, 0.f, 0.f};

  const int rr = t >> 2, cg = t & 3;      // x-staging roles
  const int grow_s = rowBase + rr;

  for (int kk0 = 0; kk0 < 128; kk0 += 32) {
    // stage x tile (64 rows x 32 k) as bf16, swizzled
    float4 v0 = make_float4(0.f, 0.f, 0.f, 0.f), v1 = v0;
    if (grow_s < NN) {
      v0 = *(const float4*)(&x[(size_t)grow_s * 128 + kk0 + cg * 8]);
      v1 = *(const float4*)(&x[(size_t)grow_s * 128 + kk0 + cg * 8 + 4]);
    }
    if (kk0) __syncthreads();   // previous tile consumed
    {
      u32 p0 = bf16pair(v0.x, v0.y);
      u32 p1 = bf16pair(v0.z, v0.w);
      u32 p2 = bf16pair(v1.x, v1.y);
      u32 p3 = bf16pair(v1.z, v1.w);
      int sg = cg ^ ((rr >> 1) & 3);
      *(uint4*)(&xsb[rr][sg * 8]) = make_uint4(p0, p1, p2, p3);
    }
    __syncthreads();

    bf16x8 bfr[2];
#pragma unroll
    for (int cf = 0; cf < 2; ++cf) {
      int col = w * 32 + cf * 16 + (l & 15);
      int kg = (kk0 >> 3) + (l >> 4);          // absolute k-group 0..15
      bfr[cf] = *(const bf16x8*)(&wsT[col][(kg ^ (col & 7)) * 8]);
    }
#pragma unroll
    for (int r = 0; r < 4; ++r) {
      int row = r * 16 + (l & 15);
      int kg = l >> 4;
      bf16x8 afr = *(const bf16x8*)(&xsb[row][(kg ^ ((row >> 1) & 3)) * 8]);
#pragma unroll
      for (int cf = 0; cf < 2; ++cf)
        acc[r][cf] = __builtin_amdgcn_mfma_f32_16x16x32_bf16(afr, bfr[cf], acc[r][cf], 0, 0, 0);
    }
  }

  // epilogue: C layout col = l&15, row = (l>>4)*4 + reg
  const int cl = l & 15;
  const int rq = l >> 4;
#pragma unroll
  for (int cf = 0; cf < 2; ++cf) {
    const int h = w * 2 + cf;
    const int gcol = w * 32 + cf * 16 + cl;
    const float as = a1[h * 32 + cl];
    const float ad = a1[h * 32 + 16 + cl];
#pragma unroll
    for (int r = 0; r < 4; ++r) {
#pragma unroll
      for (int i = 0; i < 4; ++i) {
        int grow = rowBase + r * 16 + rq * 4 + i;
        float wh = acc[r][cf][i];
        float ps = wh * as, pd = wh * ad;
        ps += __shfl_xor(ps, 1); ps += __shfl_xor(ps, 2);
        ps += __shfl_xor(ps, 4); ps += __shfl_xor(ps, 8);
        pd += __shfl_xor(pd, 1); pd += __shfl_xor(pd, 2);
        pd += __shfl_xor(pd, 4); pd += __shfl_xor(pd, 8);
        if (grow < NN) {
          Wh1b[(size_t)grow * 128 + gcol] = bf16rte(wh);
          if (cl == 0) { es1[grow * 8 + h] = ps; ed1[grow * 8 + h] = pd; }
        }
      }
    }
  }
}

// ---------------- Pass B: LDS-staged binning ----------------
__global__ __launch_bounds__(256) void k_bin(
    const int* __restrict__ src, const int* __restrict__ dst,
    int* __restrict__ cur, u32* __restrict__ ebuf)
{
  __shared__ int lcnt[512];
  __shared__ int goff[NBUCK];
  __shared__ u32 bin[4096];
  const int t = threadIdx.x;
  const int e0 = blockIdx.x * 4096;

  lcnt[t] = 0; lcnt[t + 256] = 0;
  __syncthreads();

  u32 ent[16]; short bb[16], lp[16];
#pragma unroll
  for (int i = 0; i < 16; ++i) {
    int e = e0 + i * 256 + t;
    if (e < NE) {
      int s = src[e], d = dst[e];
      int b = d >> BSH;
      ent[i] = (u32)s | ((u32)(d & 255) << 20);
      bb[i] = (short)b;
      lp[i] = (short)atomicAdd(&lcnt[b], 1);
    } else bb[i] = -1;
  }
  __syncthreads();
  for (int d = 1; d < 512; d <<= 1) {
    int v0 = (t >= d) ? lcnt[t - d] : 0;
    int v1 = (t + 256 >= d) ? lcnt[t + 256 - d] : 0;
    __syncthreads();
    lcnt[t] += v0; lcnt[t + 256] += v1;
    __syncthreads();
  }
  for (int b = t; b < NBUCK; b += 256) {
    int excl = b ? lcnt[b - 1] : 0;
    int cnt = lcnt[b] - excl;
    if (cnt) goff[b] = b * BCAP + atomicAdd(&cur[b], cnt);
  }
#pragma unroll
  for (int i = 0; i < 16; ++i) {
    if (bb[i] >= 0) {
      int excl = bb[i] ? lcnt[bb[i] - 1] : 0;
      bin[excl + lp[i]] = ent[i];
    }
  }
  __syncthreads();
  const int total = lcnt[NBUCK - 1];
  for (int i = t; i < total; i += 256) {
    int lo = 0, hi = NBUCK - 1;
    while (lo < hi) { int mid = (lo + hi) >> 1; if (lcnt[mid] > i) hi = mid; else lo = mid + 1; }
    int excl = lo ? lcnt[lo - 1] : 0;
    int g = goff[lo] + (i - excl);
    if (g < (lo + 1) * BCAP) ebuf[g] = bin[i];
  }
}

// ---------------- Pass C: per-bucket local counting sort ----------------
__global__ __launch_bounds__(256) void k_sort(
    const int* __restrict__ cur, u32* __restrict__ ebuf,
    int* __restrict__ offs, int* __restrict__ deg)
{
  __shared__ u32 ein[BCAP];
  __shared__ u32 eout[BCAP];
  __shared__ int nd[256];
  __shared__ int ncur[256];
  const int t = threadIdx.x;
  const int b = blockIdx.x;
  const int base = b * BCAP;
  int cnt = cur[b];
  if (cnt > BCAP) cnt = BCAP;
  const int nloc = min(256, NN - (b << BSH));

  for (int i = t; i < cnt; i += 256) ein[i] = ebuf[base + i];
  nd[t] = 0;
  __syncthreads();
  for (int i = t; i < cnt; i += 256) atomicAdd(&nd[ein[i] >> 20], 1);
  __syncthreads();
  const int myCnt = nd[t];
  for (int d = 1; d < 256; d <<= 1) {
    int v = (t >= d) ? nd[t - d] : 0;
    __syncthreads();
    nd[t] += v;
    __syncthreads();
  }
  const int excl = t ? nd[t - 1] : 0;
  ncur[t] = excl;
  if (t < nloc) {
    int node = (b << BSH) + t;
    offs[node] = base + excl;
    deg[node]  = myCnt;
  }
  __syncthreads();
  for (int i = t; i < cnt; i += 256) {
    u32 v = ein[i];
    int pos = atomicAdd(&ncur[v >> 20], 1);
    eout[pos] = v & 0xFFFFFu;
  }
  __syncthreads();
  for (int i = t; i < cnt; i += 256) ebuf[base + i] = eout[i];
}

// ---------------- Layer-1 aggregation: 4-deep MLP, pk_fma, h1 out bf16 ----------------
__global__ __launch_bounds__(256) void k_agg1(
    const u16* __restrict__ Wh1b, const float* __restrict__ es1, const float* __restrict__ ed1,
    const int* __restrict__ offs, const int* __restrict__ deg, const int* __restrict__ csr,
    u16* __restrict__ h1b)
{
  const int wid = threadIdx.x >> 6;
  const int lane = threadIdx.x & 63;
  const int n = blockIdx.x * 4 + wid;
  if (n >= NN) return;
  const int s0 = offs[n];
  const int nE = deg[n];
  const int g = lane >> 4;        // edge group 0..3
  const int db = lane & 15;       // dim block
  const int h = db >> 1;          // head
  const float edv = ed1[n * 8 + h];

  f32x2 acc[4];
#pragma unroll
  for (int i = 0; i < 4; ++i) { acc[i].x = 0.f; acc[i].y = 0.f; }
  float ssum = 0.f;

  int c0 = 0;
  // fast path: full 16-edge chunks, unconditional loads (4 gathers in flight)
  for (; c0 + 16 <= nE; c0 += 16) {
    int ss[4];
#pragma unroll
    for (int q = 0; q < 4; ++q) ss[q] = csr[s0 + c0 + q * 4 + g];
    float zz[4];
#pragma unroll
    for (int q = 0; q < 4; ++q) {
      float z = es1[ss[q] * 8 + h] + edv;
      zz[q] = (z > 0.f) ? z : 0.2f * z;
    }
    uint4 raw[4];
#pragma unroll
    for (int q = 0; q < 4; ++q)
      raw[q] = *(const uint4*)(Wh1b + (size_t)ss[q] * 128 + db * 8);
#pragma unroll
    for (int q = 0; q < 4; ++q) {
      const float ww = __expf(zz[q]);
      ssum += ww;
      f32x2 w2; w2.x = ww; w2.y = ww;
      pkfma(acc[0], w2, raw[q].x);
      pkfma(acc[1], w2, raw[q].y);
      pkfma(acc[2], w2, raw[q].z);
      pkfma(acc[3], w2, raw[q].w);
    }
  }
  // masked tail
  if (c0 < nE) {
    int jj[4], ss[4];
#pragma unroll
    for (int q = 0; q < 4; ++q) {
      jj[q] = c0 + q * 4 + g;
      ss[q] = csr[s0 + (jj[q] < nE ? jj[q] : 0)];
    }
    float zz[4];
#pragma unroll
    for (int q = 0; q < 4; ++q) {
      float z = es1[ss[q] * 8 + h] + edv;
      zz[q] = (z > 0.f) ? z : 0.2f * z;
    }
#pragma unroll
    for (int q = 0; q < 4; ++q) {
      if (jj[q] < nE) {
        const uint4 raw = *(const uint4*)(Wh1b + (size_t)ss[q] * 128 + db * 8);
        const float ww = __expf(zz[q]);
        ssum += ww;
        f32x2 w2; w2.x = ww; w2.y = ww;
        pkfma(acc[0], w2, raw.x);
        pkfma(acc[1], w2, raw.y);
        pkfma(acc[2], w2, raw.z);
        pkfma(acc[3], w2, raw.w);
      }
    }
  }
#pragma unroll
  for (int i = 0; i < 4; ++i) {
    acc[i].x += __shfl_xor(acc[i].x, 16);
    acc[i].y += __shfl_xor(acc[i].y, 16);
    acc[i].x += __shfl_xor(acc[i].x, 32);
    acc[i].y += __shfl_xor(acc[i].y, 32);
  }
  ssum += __shfl_xor(ssum, 16);
  ssum += __shfl_xor(ssum, 32);

  if (g == 0) {
    float inv = 1.f / (ssum + 1e-16f);
    float o[8];
#pragma unroll
    for (int i = 0; i < 4; ++i) {
      float v0 = acc[i].x * inv;
      float v1 = acc[i].y * inv;
      o[2 * i]     = (v0 > 0.f) ? v0 : expm1f(v0);
      o[2 * i + 1] = (v1 > 0.f) ? v1 : expm1f(v1);
    }
    u32 p0 = bf16pair(o[0], o[1]);
    u32 p1 = bf16pair(o[2], o[3]);
    u32 p2 = bf16pair(o[4], o[5]);
    u32 p3 = bf16pair(o[6], o[7]);
    *(uint4*)(h1b + (size_t)n * 128 + db * 8) = make_uint4(p0, p1, p2, p3);
  }
}

// ---------------- GEMM2: Wh2b(bf16, stride 48) = h1b(bf16) @ W2(128,40), fused es2/ed2 ----
__global__ __launch_bounds__(256) void k_gemm2(
    const u16* __restrict__ h1b, const float* __restrict__ W2,
    const float* __restrict__ a2,
    u16* __restrict__ Wh2b, float* __restrict__ es2, float* __restrict__ ed2)
{
  __shared__ float hs[128][36];
  __shared__ float w2s[32][40];
  const int t = threadIdx.x;
  const int rowBase = blockIdx.x * 128;
  const int cg = t & 3;
  const int rs = t >> 2;
  float acc[2][10];
#pragma unroll
  for (int r = 0; r < 2; ++r)
#pragma unroll
    for (int j = 0; j < 10; ++j) acc[r][j] = 0.f;

  for (int k0 = 0; k0 < 128; k0 += 32) {
#pragma unroll
    for (int p = 0; p < 2; ++p) {
      int idx = (p * 256 + t) * 8;
      int rr = idx >> 5, cc = idx & 31;
      int grow = rowBase + rr;
      uint4 hv = make_uint4(0u, 0u, 0u, 0u);
      if (grow < NN) hv = *(const uint4*)(h1b + (size_t)grow * 128 + k0 + cc);
      float2* dst = (float2*)&hs[rr][cc];
      dst[0] = make_float2(bflo(hv.x), bfhi(hv.x));
      dst[1] = make_float2(bflo(hv.y), bfhi(hv.y));
      dst[2] = make_float2(bflo(hv.z), bfhi(hv.z));
      dst[3] = make_float2(bflo(hv.w), bfhi(hv.w));
    }
#pragma unroll
    for (int p = 0; p < 5; ++p) {
      int idx = p * 256 + t;
      int kk = idx / 40, cc = idx % 40;
      w2s[kk][cc] = W2[(size_t)(k0 + kk) * 40 + cc];
    }
    __syncthreads();
#pragma unroll
    for (int k = 0; k < 32; ++k) {
      float a0 = hs[rs][k], a1v = hs[rs + 64][k];
#pragma unroll
      for (int j = 0; j < 10; ++j) {
        float b = w2s[k][cg * 10 + j];
        acc[0][j] = fmaf(a0, b, acc[0][j]);
        acc[1][j] = fmaf(a1v, b, acc[1][j]);
      }
    }
    __syncthreads();
  }
  float a2s[10], a2d[10];
#pragma unroll
  for (int j = 0; j < 10; ++j) {
    a2s[j] = a2[cg * 10 + j];
    a2d[j] = a2[40 + cg * 10 + j];
  }
#pragma unroll
  for (int rr = 0; rr < 2; ++rr) {
    int grow = rowBase + rs + rr * 64;
    float pes = 0.f, ped = 0.f;
#pragma unroll
    for (int j = 0; j < 10; ++j) {
      float v = acc[rr][j];
      pes = fmaf(v, a2s[j], pes);
      ped = fmaf(v, a2d[j], ped);
    }
    if (grow < NN) {
      u32* dst = (u32*)(Wh2b + (size_t)grow * 48 + cg * 10);
      dst[0] = bf16pair(acc[rr][0], acc[rr][1]);
      dst[1] = bf16pair(acc[rr][2], acc[rr][3]);
      dst[2] = bf16pair(acc[rr][4], acc[rr][5]);
      dst[3] = bf16pair(acc[rr][6], acc[rr][7]);
      dst[4] = bf16pair(acc[rr][8], acc[rr][9]);
    }
    pes += __shfl_xor(pes, 1); pes += __shfl_xor(pes, 2);
    ped += __shfl_xor(ped, 1); ped += __shfl_xor(ped, 2);
    if (cg == 0 && grow < NN) { es2[grow] = pes; ed2[grow] = ped; }
  }
}

// ---------------- Layer-2 aggregation: shuffle-free, pk_fma ----------------
__global__ __launch_bounds__(256) void k_agg2(
    const u16* __restrict__ Wh2b, const float* __restrict__ es2, const float* __restrict__ ed2,
    const int* __restrict__ offs, const int* __restrict__ deg, const int* __restrict__ csr,
    float* __restrict__ h2)
{
  __shared__ float red[4][64][9];
  const int wid = threadIdx.x >> 6;
  const int lane = threadIdx.x & 63;
  const int n = blockIdx.x * 4 + wid;
  if (n >= NN) return;
  const int s0 = offs[n];
  const int nE = deg[n];
  const float edv = ed2[n];
  const int e5 = lane / 5, r5 = lane - e5 * 5;
  const bool act = lane < 60;

  f32x2 acc[4];
#pragma unroll
  for (int i = 0; i < 4; ++i) { acc[i].x = 0.f; acc[i].y = 0.f; }
  float ssum = 0.f;

  for (int c0 = 0; c0 < nE; c0 += 24) {
    const int j0 = c0 + e5;
    const int j1 = c0 + 12 + e5;
    const int sA = csr[s0 + (j0 < nE ? j0 : 0)];
    const int sB = csr[s0 + (j1 < nE ? j1 : 0)];
    float zA = es2[sA] + edv;
    float zB = es2[sB] + edv;
    zA = (zA > 0.f) ? zA : 0.2f * zA;
    zB = (zB > 0.f) ? zB : 0.2f * zB;
    if (act && j0 < nE) {
      const uint4 raw = *(const uint4*)(Wh2b + (size_t)sA * 48 + r5 * 8);
      const float w = __expf(zA);
      ssum += w;
      f32x2 w2; w2.x = w; w2.y = w;
      pkfma(acc[0], w2, raw.x);
      pkfma(acc[1], w2, raw.y);
      pkfma(acc[2], w2, raw.z);
      pkfma(acc[3], w2, raw.w);
    }
    if (act && j1 < nE) {
      const uint4 raw = *(const uint4*)(Wh2b + (size_t)sB * 48 + r5 * 8);
      const float w = __expf(zB);
      ssum += w;
      f32x2 w2; w2.x = w; w2.y = w;
      pkfma(acc[0], w2, raw.x);
      pkfma(acc[1], w2, raw.y);
      pkfma(acc[2], w2, raw.z);
      pkfma(acc[3], w2, raw.w);
    }
  }
#pragma unroll
  for (int i = 0; i < 4; ++i) {
    red[wid][lane][2 * i]     = acc[i].x;
    red[wid][lane][2 * i + 1] = acc[i].y;
  }
  red[wid][lane][8] = ssum;
  __builtin_amdgcn_wave_barrier();
  if (lane < 40) {
    int slot = lane >> 3, i = lane & 7;
    float a = 0.f, sm = 0.f;
#pragma unroll
    for (int g = 0; g < 12; ++g) {
      a  += red[wid][g * 5 + slot][i];
      sm += red[wid][g * 5][8];
    }
    h2[(size_t)n * 40 + lane] = a / (sm + 1e-16f);
  }
}

// ---------------- Pooling ----------------
__global__ void k_gbounds(const int* __restrict__ batch, int* __restrict__ gstart) {
  int g = threadIdx.x;
  if (g > NG) return;
  int lo = 0, hi = NN;
  while (lo < hi) { int mid = (lo + hi) >> 1; if (batch[mid] < g) lo = mid + 1; else hi = mid; }
  gstart[g] = lo;
}

__global__ __launch_bounds__(256) void k_pool1(
    const float* __restrict__ h2, const int* __restrict__ gstart,
    float* __restrict__ partial)
{
  __shared__ float lds[25][10][4];
  const int g = blockIdx.x >> 3;
  const int p = blockIdx.x & 7;
  const int t = threadIdx.x;
  const int s0 = gstart[g], s1 = gstart[g + 1];
  const int len = s1 - s0;
  const int chunk = (len + PB - 1) / PB;
  const int start = s0 + p * chunk;
  const int end = min(start + chunk, s1);
  const int slot = t / 10, q = t - slot * 10;
  float4 acc = make_float4(0.f, 0.f, 0.f, 0.f);
  if (slot < 25) {
    for (int n = start + slot; n < end; n += 25) {
      const float4 v = *(const float4*)(&h2[(size_t)n * 40 + q * 4]);
      acc.x += v.x; acc.y += v.y; acc.z += v.z; acc.w += v.w;
    }
    lds[slot][q][0] = acc.x; lds[slot][q][1] = acc.y;
    lds[slot][q][2] = acc.z; lds[slot][q][3] = acc.w;
  }
  __syncthreads();
  if (t < 40) {
    const int qq = t >> 2, e = t & 3;
    float s = 0.f;
#pragma unroll
    for (int sl = 0; sl < 25; ++sl) s += lds[sl][qq][e];
    partial[(size_t)blockIdx.x * 40 + t] = s;
  }
}

__global__ void k_pool2(const float* __restrict__ partial, const int* __restrict__ gstart,
                        float* __restrict__ out)
{
  const int g = blockIdx.x;
  const int d = threadIdx.x;
  if (d >= 40) return;
  float s = 0.f;
#pragma unroll
  for (int p = 0; p < PB; ++p) s += partial[(size_t)(g * PB + p) * 40 + d];
  int cnt = gstart[g + 1] - gstart[g];
  if (cnt < 1) cnt = 1;
  out[g * 40 + d] = s / (float)cnt;
}

extern "C" void kernel_launch(void* const* d_in, const int* in_sizes, int n_in,
                              void* d_out, int out_size, void* d_ws, size_t ws_size,
                              hipStream_t stream)
{
  const float* x   = (const float*)d_in[0];
  const float* W1  = (const float*)d_in[1];
  const float* a1  = (const float*)d_in[2];
  const float* W2  = (const float*)d_in[3];
  const float* a2  = (const float*)d_in[4];
  const int* eidx  = (const int*)d_in[5];
  const int* batch = (const int*)d_in[6];
  float* out = (float*)d_out;

  char* ws = (char*)d_ws;
  u16*   Wh1b = (u16*)(ws + 0);              // 25,600,000 B
  u16*   Wh2b = (u16*)(ws + 0);              //  9,600,000 B (reuse after agg1)
  float* h2   = (float*)(ws + 9600000);      // 16,000,000 B (reuse)
  u16*   h1b  = (u16*)(ws + 25600000);       // 25,600,000 B
  float* es1  = (float*)(ws + 51200000);     //  3,200,000
  float* ed1  = (float*)(ws + 54400000);     //  3,200,000
  float* es2  = (float*)(ws + 57600000);     //    400,000
  float* ed2  = (float*)(ws + 58000000);     //    400,000
  u32*   ebuf = (u32*)(ws + 58400000);       //  8,007,680 (NBUCK*BCAP*4) -> becomes csr
  int*   offs = (int*)(ws + 66407680);       //    400,000
  int*   deg  = (int*)(ws + 66807680);       //    400,000
  int*   cur  = (int*)(ws + 67207680);       //      2,048
  int*   gstart = (int*)(ws + 67209728);     //        512
  float* partial = (float*)(ws + 67210240);  //     81,920
  u16*   wsTg = (u16*)(ws + 67292160);       //     32,768 (bf16 swizzled W1^T)
  // total ~67.3 MB

  const int* esrc = eidx;
  const int* edst = eidx + NE;

  hipMemsetAsync(cur, 0, NBUCK * sizeof(int), stream);
  k_prepW<<<1, 256, 0, stream>>>(W1, wsTg);
  k_gbounds<<<1, 128, 0, stream>>>(batch, gstart);
  k_gemm1<<<(NN + 63) / 64, 256, 0, stream>>>(x, wsTg, a1, Wh1b, es1, ed1);
  k_bin<<<(NE + 4095) / 4096, 256, 0, stream>>>(esrc, edst, cur, ebuf);
  k_sort<<<NBUCK, 256, 0, stream>>>(cur, ebuf, offs, deg);
  k_agg1<<<(NN + 3) / 4, 256, 0, stream>>>(Wh1b, es1, ed1, offs, deg, (const int*)ebuf, h1b);
  k_gemm2<<<(NN + 127) / 128, 256, 0, stream>>>(h1b, W2, a2, Wh2b, es2, ed2);
  k_agg2<<<(NN + 3) / 4, 256, 0, stream>>>(Wh2b, es2, ed2, offs, deg, (const int*)ebuf, h2);
  k_pool1<<<NG * PB, 256, 0, stream>>>(h2, gstart, partial);
  k_pool2<<<NG, 64, 0, stream>>>(partial, gstart, out);
}

// Round 10
// 256.784 us; speedup vs baseline: 1.5114x; 1.0394x over previous
//
#include <hip/hip_runtime.h>
#include <hip/hip_bf16.h>

typedef unsigned short u16;
typedef unsigned int   u32;
typedef float f32x2 __attribute__((ext_vector_type(2)));
typedef float f32x4 __attribute__((ext_vector_type(4)));
typedef short bf16x8 __attribute__((ext_vector_type(8)));

static constexpr int NN = 100000;   // nodes
static constexpr int NE = 1600000;  // edges
static constexpr int NG = 64;       // graphs

static constexpr int BSH   = 8;     // nodes per bucket = 256
static constexpr int NBUCK = 391;   // ceil(NN / 256)
static constexpr int BCAP  = 5120;  // bucket capacity (mean 4096, sd ~64)
static constexpr int PB    = 8;     // pooling partial-blocks per graph

// RTNE f32->bf16
__device__ __forceinline__ u16 bf16rte(float a) {
  u32 u = __builtin_bit_cast(u32, a);
  u = (u + 0x7FFFu + ((u >> 16) & 1u)) >> 16;
  return (u16)u;
}
__device__ __forceinline__ u32 bf16pair(float a, float b) {
  return (u32)bf16rte(a) | ((u32)bf16rte(b) << 16);
}
__device__ __forceinline__ float bflo(u32 u) { return __builtin_bit_cast(float, u << 16); }
__device__ __forceinline__ float bfhi(u32 u) { return __builtin_bit_cast(float, u & 0xFFFF0000u); }

// packed dual-FMA: a.lo += w.lo*bflo(u); a.hi += w.hi*bfhi(u)
__device__ __forceinline__ void pkfma(f32x2& a, f32x2 w2, u32 u) {
  f32x2 v;
  v.x = bflo(u); v.y = bfhi(u);
  asm("v_pk_fma_f32 %0, %1, %2, %0" : "+v"(a) : "v"(w2), "v"(v));
}

// ---------------- prep: W1 -> bf16 swizzled (blocks 0..63) | gbounds (block 64) ----------
__global__ void k_prep(const float* __restrict__ W1, u16* __restrict__ wsTg,
                       const int* __restrict__ batch, int* __restrict__ gstart) {
  const int bid = blockIdx.x;
  if (bid < 64) {
    int idx = bid * 256 + threadIdx.x;   // 64*256 = 16384 = all of W1
    int k = idx >> 7, c = idx & 127;
    wsTg[c * 128 + (((k >> 3) ^ (c & 7)) << 3) + (k & 7)] = bf16rte(W1[idx]);
  } else {
    int g = threadIdx.x;
    if (g <= NG) {
      int lo = 0, hi = NN;
      while (lo < hi) { int mid = (lo + hi) >> 1; if (batch[mid] < g) lo = mid + 1; else hi = mid; }
      gstart[g] = lo;
    }
  }
}

// ---------------- GEMM1 (MFMA bf16): Wh1b = x @ W1, fused es1/ed1 ----------------
__global__ __launch_bounds__(256) void k_gemm1(
    const float* __restrict__ x, const u16* __restrict__ wsTg, const float* __restrict__ a1,
    u16* __restrict__ Wh1b, float* __restrict__ es1, float* __restrict__ ed1)
{
  __shared__ u16 wsT[128][128];   // [col][k], kg' = kg ^ (col&7)  (32 KB)
  __shared__ u16 xsb[64][32];     // [row][k-in-step], kg' = kg ^ ((row>>1)&3)  (4 KB)
  const int t = threadIdx.x;
  const int w = t >> 6, l = t & 63;
  const int rowBase = blockIdx.x * 64;

  // stage swizzled W1^T (bf16) linearly: 32 KB, 128 B/thread
  {
    const uint4* src = (const uint4*)wsTg;
    uint4* dst = (uint4*)&wsT[0][0];
#pragma unroll
    for (int i = 0; i < 8; ++i) dst[t * 8 + i] = src[t * 8 + i];
  }

  f32x4 acc[4][2];
#pragma unroll
  for (int r = 0; r < 4; ++r)
#pragma unroll
    for (int cf = 0; cf < 2; ++cf) acc[r][cf] = (f32x4){0.f, 0.f, 0.f, 0.f};

  const int rr = t >> 2, cg = t & 3;      // x-staging roles
  const int grow_s = rowBase + rr;

  for (int kk0 = 0; kk0 < 128; kk0 += 32) {
    // stage x tile (64 rows x 32 k) as bf16, swizzled
    float4 v0 = make_float4(0.f, 0.f, 0.f, 0.f), v1 = v0;
    if (grow_s < NN) {
      v0 = *(const float4*)(&x[(size_t)grow_s * 128 + kk0 + cg * 8]);
      v1 = *(const float4*)(&x[(size_t)grow_s * 128 + kk0 + cg * 8 + 4]);
    }
    if (kk0) __syncthreads();   // previous tile consumed
    {
      u32 p0 = bf16pair(v0.x, v0.y);
      u32 p1 = bf16pair(v0.z, v0.w);
      u32 p2 = bf16pair(v1.x, v1.y);
      u32 p3 = bf16pair(v1.z, v1.w);
      int sg = cg ^ ((rr >> 1) & 3);
      *(uint4*)(&xsb[rr][sg * 8]) = make_uint4(p0, p1, p2, p3);
    }
    __syncthreads();

    bf16x8 bfr[2];
#pragma unroll
    for (int cf = 0; cf < 2; ++cf) {
      int col = w * 32 + cf * 16 + (l & 15);
      int kg = (kk0 >> 3) + (l >> 4);          // absolute k-group 0..15
      bfr[cf] = *(const bf16x8*)(&wsT[col][(kg ^ (col & 7)) * 8]);
    }
#pragma unroll
    for (int r = 0; r < 4; ++r) {
      int row = r * 16 + (l & 15);
      int kg = l >> 4;
      bf16x8 afr = *(const bf16x8*)(&xsb[row][(kg ^ ((row >> 1) & 3)) * 8]);
#pragma unroll
      for (int cf = 0; cf < 2; ++cf)
        acc[r][cf] = __builtin_amdgcn_mfma_f32_16x16x32_bf16(afr, bfr[cf], acc[r][cf], 0, 0, 0);
    }
  }

  // epilogue: C layout col = l&15, row = (l>>4)*4 + reg
  const int cl = l & 15;
  const int rq = l >> 4;
#pragma unroll
  for (int cf = 0; cf < 2; ++cf) {
    const int h = w * 2 + cf;
    const int gcol = w * 32 + cf * 16 + cl;
    const float as = a1[h * 32 + cl];
    const float ad = a1[h * 32 + 16 + cl];
#pragma unroll
    for (int r = 0; r < 4; ++r) {
#pragma unroll
      for (int i = 0; i < 4; ++i) {
        int grow = rowBase + r * 16 + rq * 4 + i;
        float wh = acc[r][cf][i];
        float ps = wh * as, pd = wh * ad;
        ps += __shfl_xor(ps, 1); ps += __shfl_xor(ps, 2);
        ps += __shfl_xor(ps, 4); ps += __shfl_xor(ps, 8);
        pd += __shfl_xor(pd, 1); pd += __shfl_xor(pd, 2);
        pd += __shfl_xor(pd, 4); pd += __shfl_xor(pd, 8);
        if (grow < NN) {
          Wh1b[(size_t)grow * 128 + gcol] = bf16rte(wh);
          if (cl == 0) { es1[grow * 8 + h] = ps; ed1[grow * 8 + h] = pd; }
        }
      }
    }
  }
}

// ---------------- Pass B: LDS-staged binning ----------------
__global__ __launch_bounds__(256) void k_bin(
    const int* __restrict__ src, const int* __restrict__ dst,
    int* __restrict__ cur, u32* __restrict__ ebuf)
{
  __shared__ int lcnt[512];
  __shared__ int goff[NBUCK];
  __shared__ u32 bin[4096];
  const int t = threadIdx.x;
  const int e0 = blockIdx.x * 4096;

  lcnt[t] = 0; lcnt[t + 256] = 0;
  __syncthreads();

  u32 ent[16]; short bb[16], lp[16];
#pragma unroll
  for (int i = 0; i < 16; ++i) {
    int e = e0 + i * 256 + t;
    if (e < NE) {
      int s = src[e], d = dst[e];
      int b = d >> BSH;
      ent[i] = (u32)s | ((u32)(d & 255) << 20);
      bb[i] = (short)b;
      lp[i] = (short)atomicAdd(&lcnt[b], 1);
    } else bb[i] = -1;
  }
  __syncthreads();
  for (int d = 1; d < 512; d <<= 1) {
    int v0 = (t >= d) ? lcnt[t - d] : 0;
    int v1 = (t + 256 >= d) ? lcnt[t + 256 - d] : 0;
    __syncthreads();
    lcnt[t] += v0; lcnt[t + 256] += v1;
    __syncthreads();
  }
  for (int b = t; b < NBUCK; b += 256) {
    int excl = b ? lcnt[b - 1] : 0;
    int cnt = lcnt[b] - excl;
    if (cnt) goff[b] = b * BCAP + atomicAdd(&cur[b], cnt);
  }
#pragma unroll
  for (int i = 0; i < 16; ++i) {
    if (bb[i] >= 0) {
      int excl = bb[i] ? lcnt[bb[i] - 1] : 0;
      bin[excl + lp[i]] = ent[i];
    }
  }
  __syncthreads();
  const int total = lcnt[NBUCK - 1];
  for (int i = t; i < total; i += 256) {
    int lo = 0, hi = NBUCK - 1;
    while (lo < hi) { int mid = (lo + hi) >> 1; if (lcnt[mid] > i) hi = mid; else lo = mid + 1; }
    int excl = lo ? lcnt[lo - 1] : 0;
    int g = goff[lo] + (i - excl);
    if (g < (lo + 1) * BCAP) ebuf[g] = bin[i];
  }
}

// ---------------- Pass C: per-bucket local counting sort ----------------
__global__ __launch_bounds__(256) void k_sort(
    const int* __restrict__ cur, u32* __restrict__ ebuf,
    int* __restrict__ offs, int* __restrict__ deg)
{
  __shared__ u32 ein[BCAP];
  __shared__ u32 eout[BCAP];
  __shared__ int nd[256];
  __shared__ int ncur[256];
  const int t = threadIdx.x;
  const int b = blockIdx.x;
  const int base = b * BCAP;
  int cnt = cur[b];
  if (cnt > BCAP) cnt = BCAP;
  const int nloc = min(256, NN - (b << BSH));

  for (int i = t; i < cnt; i += 256) ein[i] = ebuf[base + i];
  nd[t] = 0;
  __syncthreads();
  for (int i = t; i < cnt; i += 256) atomicAdd(&nd[ein[i] >> 20], 1);
  __syncthreads();
  const int myCnt = nd[t];
  for (int d = 1; d < 256; d <<= 1) {
    int v = (t >= d) ? nd[t - d] : 0;
    __syncthreads();
    nd[t] += v;
    __syncthreads();
  }
  const int excl = t ? nd[t - 1] : 0;
  ncur[t] = excl;
  if (t < nloc) {
    int node = (b << BSH) + t;
    offs[node] = base + excl;
    deg[node]  = myCnt;
  }
  __syncthreads();
  for (int i = t; i < cnt; i += 256) {
    u32 v = ein[i];
    int pos = atomicAdd(&ncur[v >> 20], 1);
    eout[pos] = v & 0xFFFFFu;
  }
  __syncthreads();
  for (int i = t; i < cnt; i += 256) ebuf[base + i] = eout[i];
}

// ---------------- Layer-1 aggregation: 4-deep MLP, pk_fma, h1 out bf16 ----------------
__global__ __launch_bounds__(256, 8) void k_agg1(
    const u16* __restrict__ Wh1b, const float* __restrict__ es1, const float* __restrict__ ed1,
    const int* __restrict__ offs, const int* __restrict__ deg, const int* __restrict__ csr,
    u16* __restrict__ h1b)
{
  const int wid = threadIdx.x >> 6;
  const int lane = threadIdx.x & 63;
  const int n = blockIdx.x * 4 + wid;
  if (n >= NN) return;
  const int s0 = offs[n];
  const int nE = deg[n];
  const int g = lane >> 4;        // edge group 0..3
  const int db = lane & 15;       // dim block
  const int h = db >> 1;          // head
  const float edv = ed1[n * 8 + h];

  f32x2 acc[4];
#pragma unroll
  for (int i = 0; i < 4; ++i) { acc[i].x = 0.f; acc[i].y = 0.f; }
  float ssum = 0.f;

  int c0 = 0;
  // fast path: full 16-edge chunks, unconditional loads (4 gathers in flight)
  for (; c0 + 16 <= nE; c0 += 16) {
    int ss[4];
#pragma unroll
    for (int q = 0; q < 4; ++q) ss[q] = csr[s0 + c0 + q * 4 + g];
    float zz[4];
#pragma unroll
    for (int q = 0; q < 4; ++q) {
      float z = es1[ss[q] * 8 + h] + edv;
      zz[q] = (z > 0.f) ? z : 0.2f * z;
    }
    uint4 raw[4];
#pragma unroll
    for (int q = 0; q < 4; ++q)
      raw[q] = *(const uint4*)(Wh1b + (size_t)ss[q] * 128 + db * 8);
#pragma unroll
    for (int q = 0; q < 4; ++q) {
      const float ww = __expf(zz[q]);
      ssum += ww;
      f32x2 w2; w2.x = ww; w2.y = ww;
      pkfma(acc[0], w2, raw[q].x);
      pkfma(acc[1], w2, raw[q].y);
      pkfma(acc[2], w2, raw[q].z);
      pkfma(acc[3], w2, raw[q].w);
    }
  }
  // masked tail
  if (c0 < nE) {
    int jj[4], ss[4];
#pragma unroll
    for (int q = 0; q < 4; ++q) {
      jj[q] = c0 + q * 4 + g;
      ss[q] = csr[s0 + (jj[q] < nE ? jj[q] : 0)];
    }
    float zz[4];
#pragma unroll
    for (int q = 0; q < 4; ++q) {
      float z = es1[ss[q] * 8 + h] + edv;
      zz[q] = (z > 0.f) ? z : 0.2f * z;
    }
#pragma unroll
    for (int q = 0; q < 4; ++q) {
      if (jj[q] < nE) {
        const uint4 raw = *(const uint4*)(Wh1b + (size_t)ss[q] * 128 + db * 8);
        const float ww = __expf(zz[q]);
        ssum += ww;
        f32x2 w2; w2.x = ww; w2.y = ww;
        pkfma(acc[0], w2, raw.x);
        pkfma(acc[1], w2, raw.y);
        pkfma(acc[2], w2, raw.z);
        pkfma(acc[3], w2, raw.w);
      }
    }
  }
#pragma unroll
  for (int i = 0; i < 4; ++i) {
    acc[i].x += __shfl_xor(acc[i].x, 16);
    acc[i].y += __shfl_xor(acc[i].y, 16);
    acc[i].x += __shfl_xor(acc[i].x, 32);
    acc[i].y += __shfl_xor(acc[i].y, 32);
  }
  ssum += __shfl_xor(ssum, 16);
  ssum += __shfl_xor(ssum, 32);

  if (g == 0) {
    float inv = 1.f / (ssum + 1e-16f);
    float o[8];
#pragma unroll
    for (int i = 0; i < 4; ++i) {
      float v0 = acc[i].x * inv;
      float v1 = acc[i].y * inv;
      o[2 * i]     = (v0 > 0.f) ? v0 : expm1f(v0);
      o[2 * i + 1] = (v1 > 0.f) ? v1 : expm1f(v1);
    }
    u32 p0 = bf16pair(o[0], o[1]);
    u32 p1 = bf16pair(o[2], o[3]);
    u32 p2 = bf16pair(o[4], o[5]);
    u32 p3 = bf16pair(o[6], o[7]);
    *(uint4*)(h1b + (size_t)n * 128 + db * 8) = make_uint4(p0, p1, p2, p3);
  }
}

// ---------------- GEMM2: Wh2b(bf16, stride 48) = h1b(bf16) @ W2(128,40), fused es2/ed2 ----
__global__ __launch_bounds__(256) void k_gemm2(
    const u16* __restrict__ h1b, const float* __restrict__ W2,
    const float* __restrict__ a2,
    u16* __restrict__ Wh2b, float* __restrict__ es2, float* __restrict__ ed2)
{
  __shared__ float hs[128][36];
  __shared__ float w2s[32][40];
  const int t = threadIdx.x;
  const int rowBase = blockIdx.x * 128;
  const int cg = t & 3;
  const int rs = t >> 2;
  float acc[2][10];
#pragma unroll
  for (int r = 0; r < 2; ++r)
#pragma unroll
    for (int j = 0; j < 10; ++j) acc[r][j] = 0.f;

  for (int k0 = 0; k0 < 128; k0 += 32) {
#pragma unroll
    for (int p = 0; p < 2; ++p) {
      int idx = (p * 256 + t) * 8;
      int rr = idx >> 5, cc = idx & 31;
      int grow = rowBase + rr;
      uint4 hv = make_uint4(0u, 0u, 0u, 0u);
      if (grow < NN) hv = *(const uint4*)(h1b + (size_t)grow * 128 + k0 + cc);
      float2* dst = (float2*)&hs[rr][cc];
      dst[0] = make_float2(bflo(hv.x), bfhi(hv.x));
      dst[1] = make_float2(bflo(hv.y), bfhi(hv.y));
      dst[2] = make_float2(bflo(hv.z), bfhi(hv.z));
      dst[3] = make_float2(bflo(hv.w), bfhi(hv.w));
    }
#pragma unroll
    for (int p = 0; p < 5; ++p) {
      int idx = p * 256 + t;
      int kk = idx / 40, cc = idx % 40;
      w2s[kk][cc] = W2[(size_t)(k0 + kk) * 40 + cc];
    }
    __syncthreads();
#pragma unroll
    for (int k = 0; k < 32; ++k) {
      float a0 = hs[rs][k], a1v = hs[rs + 64][k];
#pragma unroll
      for (int j = 0; j < 10; ++j) {
        float b = w2s[k][cg * 10 + j];
        acc[0][j] = fmaf(a0, b, acc[0][j]);
        acc[1][j] = fmaf(a1v, b, acc[1][j]);
      }
    }
    __syncthreads();
  }
  float a2s[10], a2d[10];
#pragma unroll
  for (int j = 0; j < 10; ++j) {
    a2s[j] = a2[cg * 10 + j];
    a2d[j] = a2[40 + cg * 10 + j];
  }
#pragma unroll
  for (int rr = 0; rr < 2; ++rr) {
    int grow = rowBase + rs + rr * 64;
    float pes = 0.f, ped = 0.f;
#pragma unroll
    for (int j = 0; j < 10; ++j) {
      float v = acc[rr][j];
      pes = fmaf(v, a2s[j], pes);
      ped = fmaf(v, a2d[j], ped);
    }
    if (grow < NN) {
      u32* dst = (u32*)(Wh2b + (size_t)grow * 48 + cg * 10);
      dst[0] = bf16pair(acc[rr][0], acc[rr][1]);
      dst[1] = bf16pair(acc[rr][2], acc[rr][3]);
      dst[2] = bf16pair(acc[rr][4], acc[rr][5]);
      dst[3] = bf16pair(acc[rr][6], acc[rr][7]);
      dst[4] = bf16pair(acc[rr][8], acc[rr][9]);
    }
    pes += __shfl_xor(pes, 1); pes += __shfl_xor(pes, 2);
    ped += __shfl_xor(ped, 1); ped += __shfl_xor(ped, 2);
    if (cg == 0 && grow < NN) { es2[grow] = pes; ed2[grow] = ped; }
  }
}

// ---------------- Layer-2 aggregation: 6 edge-groups x 10 dim-lanes, 4-deep MLP ----------
__global__ __launch_bounds__(256, 8) void k_agg2(
    const u16* __restrict__ Wh2b, const float* __restrict__ es2, const float* __restrict__ ed2,
    const int* __restrict__ offs, const int* __restrict__ deg, const int* __restrict__ csr,
    float* __restrict__ h2)
{
  __shared__ float red[4][64][5];
  const int wid = threadIdx.x >> 6;
  const int lane = threadIdx.x & 63;
  const int n = blockIdx.x * 4 + wid;
  if (n >= NN) return;
  const int s0 = offs[n];
  const int nE = deg[n];
  const float edv = ed2[n];
  int e6 = lane / 10;               // edge group 0..6 (tail lanes clamp)
  const int r10 = lane - e6 * 10;   // dim block 0..9 (4 dims each)
  const bool act = lane < 60;
  if (e6 > 5) e6 = 5;

  f32x2 acc0, acc1;
  acc0.x = acc0.y = acc1.x = acc1.y = 0.f;
  float ssum = 0.f;

  for (int c0 = 0; c0 < nE; c0 += 24) {
    int jj[4], ss[4];
#pragma unroll
    for (int q = 0; q < 4; ++q) {
      jj[q] = c0 + q * 6 + e6;
      ss[q] = csr[s0 + (jj[q] < nE ? jj[q] : 0)];
    }
    float zz[4];
#pragma unroll
    for (int q = 0; q < 4; ++q) {
      float z = es2[ss[q]] + edv;
      zz[q] = (z > 0.f) ? z : 0.2f * z;
    }
#pragma unroll
    for (int q = 0; q < 4; ++q) {
      if (act && jj[q] < nE) {
        const uint2 raw = *(const uint2*)(Wh2b + (size_t)ss[q] * 48 + r10 * 4);
        const float ww = __expf(zz[q]);
        ssum += ww;
        f32x2 w2; w2.x = ww; w2.y = ww;
        pkfma(acc0, w2, raw.x);
        pkfma(acc1, w2, raw.y);
      }
    }
  }
  red[wid][lane][0] = acc0.x; red[wid][lane][1] = acc0.y;
  red[wid][lane][2] = acc1.x; red[wid][lane][3] = acc1.y;
  red[wid][lane][4] = ssum;
  __builtin_amdgcn_wave_barrier();
  if (lane < 40) {
    const int rb = lane >> 2, e = lane & 3;
    float a = 0.f, sm = 0.f;
#pragma unroll
    for (int g = 0; g < 6; ++g) {
      a  += red[wid][g * 10 + rb][e];
      sm += red[wid][g * 10][4];
    }
    h2[(size_t)n * 40 + lane] = a / (sm + 1e-16f);
  }
}

// ---------------- Pooling ----------------
__global__ __launch_bounds__(256) void k_pool1(
    const float* __restrict__ h2, const int* __restrict__ gstart,
    float* __restrict__ partial)
{
  __shared__ float lds[25][10][4];
  const int g = blockIdx.x >> 3;
  const int p = blockIdx.x & 7;
  const int t = threadIdx.x;
  const int s0 = gstart[g], s1 = gstart[g + 1];
  const int len = s1 - s0;
  const int chunk = (len + PB - 1) / PB;
  const int start = s0 + p * chunk;
  const int end = min(start + chunk, s1);
  const int slot = t / 10, q = t - slot * 10;
  float4 acc = make_float4(0.f, 0.f, 0.f, 0.f);
  if (slot < 25) {
    for (int n = start + slot; n < end; n += 25) {
      const float4 v = *(const float4*)(&h2[(size_t)n * 40 + q * 4]);
      acc.x += v.x; acc.y += v.y; acc.z += v.z; acc.w += v.w;
    }
    lds[slot][q][0] = acc.x; lds[slot][q][1] = acc.y;
    lds[slot][q][2] = acc.z; lds[slot][q][3] = acc.w;
  }
  __syncthreads();
  if (t < 40) {
    const int qq = t >> 2, e = t & 3;
    float s = 0.f;
#pragma unroll
    for (int sl = 0; sl < 25; ++sl) s += lds[sl][qq][e];
    partial[(size_t)blockIdx.x * 40 + t] = s;
  }
}

__global__ void k_pool2(const float* __restrict__ partial, const int* __restrict__ gstart,
                        float* __restrict__ out)
{
  const int g = blockIdx.x;
  const int d = threadIdx.x;
  if (d >= 40) return;
  float s = 0.f;
#pragma unroll
  for (int p = 0; p < PB; ++p) s += partial[(size_t)(g * PB + p) * 40 + d];
  int cnt = gstart[g + 1] - gstart[g];
  if (cnt < 1) cnt = 1;
  out[g * 40 + d] = s / (float)cnt;
}

extern "C" void kernel_launch(void* const* d_in, const int* in_sizes, int n_in,
                              void* d_out, int out_size, void* d_ws, size_t ws_size,
                              hipStream_t stream)
{
  const float* x   = (const float*)d_in[0];
  const float* W1  = (const float*)d_in[1];
  const float* a1  = (const float*)d_in[2];
  const float* W2  = (const float*)d_in[3];
  const float* a2  = (const float*)d_in[4];
  const int* eidx  = (const int*)d_in[5];
  const int* batch = (const int*)d_in[6];
  float* out = (float*)d_out;

  char* ws = (char*)d_ws;
  u16*   Wh1b = (u16*)(ws + 0);              // 25,600,000 B
  u16*   Wh2b = (u16*)(ws + 0);              //  9,600,000 B (reuse after agg1)
  float* h2   = (float*)(ws + 9600000);      // 16,000,000 B (reuse)
  u16*   h1b  = (u16*)(ws + 25600000);       // 25,600,000 B
  float* es1  = (float*)(ws + 51200000);     //  3,200,000
  float* ed1  = (float*)(ws + 54400000);     //  3,200,000
  float* es2  = (float*)(ws + 57600000);     //    400,000
  float* ed2  = (float*)(ws + 58000000);     //    400,000
  u32*   ebuf = (u32*)(ws + 58400000);       //  8,007,680 (NBUCK*BCAP*4) -> becomes csr
  int*   offs = (int*)(ws + 66407680);       //    400,000
  int*   deg  = (int*)(ws + 66807680);       //    400,000
  int*   cur  = (int*)(ws + 67207680);       //      2,048
  int*   gstart = (int*)(ws + 67209728);     //        512
  float* partial = (float*)(ws + 67210240);  //     81,920
  u16*   wsTg = (u16*)(ws + 67292160);       //     32,768 (bf16 swizzled W1^T)
  // total ~67.3 MB

  const int* esrc = eidx;
  const int* edst = eidx + NE;

  hipMemsetAsync(cur, 0, NBUCK * sizeof(int), stream);
  k_prep<<<65, 256, 0, stream>>>(W1, wsTg, batch, gstart);
  k_gemm1<<<(NN + 63) / 64, 256, 0, stream>>>(x, wsTg, a1, Wh1b, es1, ed1);
  k_bin<<<(NE + 4095) / 4096, 256, 0, stream>>>(esrc, edst, cur, ebuf);
  k_sort<<<NBUCK, 256, 0, stream>>>(cur, ebuf, offs, deg);
  k_agg1<<<(NN + 3) / 4, 256, 0, stream>>>(Wh1b, es1, ed1, offs, deg, (const int*)ebuf, h1b);
  k_gemm2<<<(NN + 127) / 128, 256, 0, stream>>>(h1b, W2, a2, Wh2b, es2, ed2);
  k_agg2<<<(NN + 3) / 4, 256, 0, stream>>>(Wh2b, es2, ed2, offs, deg, (const int*)ebuf, h2);
  k_pool1<<<NG * PB, 256, 0, stream>>>(h2, gstart, partial);
  k_pool2<<<NG, 64, 0, stream>>>(partial, gstart, out);
}

// Round 11
// 250.586 us; speedup vs baseline: 1.5487x; 1.0247x over previous
//
#include <hip/hip_runtime.h>
#include <hip/hip_bf16.h>

typedef unsigned short u16;
typedef unsigned int   u32;
typedef float f32x2 __attribute__((ext_vector_type(2)));
typedef float f32x4 __attribute__((ext_vector_type(4)));
typedef short bf16x8 __attribute__((ext_vector_type(8)));

static constexpr int NN = 100000;   // nodes
static constexpr int NE = 1600000;  // edges
static constexpr int NG = 64;       // graphs

static constexpr int BSH   = 8;     // nodes per bucket = 256
static constexpr int NBUCK = 391;   // ceil(NN / 256)
static constexpr int BCAP  = 5120;  // bucket capacity (mean 4096, sd ~64)
static constexpr int PB    = 8;     // pooling partial-blocks per graph

// RTNE f32->bf16
__device__ __forceinline__ u16 bf16rte(float a) {
  u32 u = __builtin_bit_cast(u32, a);
  u = (u + 0x7FFFu + ((u >> 16) & 1u)) >> 16;
  return (u16)u;
}
__device__ __forceinline__ u32 bf16pair(float a, float b) {
  return (u32)bf16rte(a) | ((u32)bf16rte(b) << 16);
}
__device__ __forceinline__ float bflo(u32 u) { return __builtin_bit_cast(float, u << 16); }
__device__ __forceinline__ float bfhi(u32 u) { return __builtin_bit_cast(float, u & 0xFFFF0000u); }

// packed dual-FMA: a.lo += w.lo*bflo(u); a.hi += w.hi*bfhi(u)
__device__ __forceinline__ void pkfma(f32x2& a, f32x2 w2, u32 u) {
  f32x2 v;
  v.x = bflo(u); v.y = bfhi(u);
  asm("v_pk_fma_f32 %0, %1, %2, %0" : "+v"(a) : "v"(w2), "v"(v));
}

// ---- prep: W1 -> bf16 swizzled (blocks 0..63) | gbounds + cur-zero (block 64) ----
__global__ void k_prep(const float* __restrict__ W1, u16* __restrict__ wsTg,
                       const int* __restrict__ batch, int* __restrict__ gstart,
                       int* __restrict__ cur) {
  const int bid = blockIdx.x;
  if (bid < 64) {
    int idx = bid * 256 + threadIdx.x;   // 64*256 = 16384 = all of W1
    int k = idx >> 7, c = idx & 127;
    wsTg[c * 128 + (((k >> 3) ^ (c & 7)) << 3) + (k & 7)] = bf16rte(W1[idx]);
  } else {
    int t = threadIdx.x;
    for (int i = t; i < NBUCK; i += 256) cur[i] = 0;
    if (t <= NG) {
      int lo = 0, hi = NN;
      while (lo < hi) { int mid = (lo + hi) >> 1; if (batch[mid] < t) lo = mid + 1; else hi = mid; }
      gstart[t] = lo;
    }
  }
}

// ---------------- GEMM1 (MFMA bf16): Wh1b = x @ W1, fused es1/ed1 ----------------
__global__ __launch_bounds__(256) void k_gemm1(
    const float* __restrict__ x, const u16* __restrict__ wsTg, const float* __restrict__ a1,
    u16* __restrict__ Wh1b, float* __restrict__ es1, float* __restrict__ ed1)
{
  __shared__ u16 wsT[128][128];   // [col][k], kg' = kg ^ (col&7)  (32 KB)
  __shared__ u16 xsb[64][32];     // [row][k-in-step], kg' = kg ^ ((row>>1)&3)  (4 KB)
  const int t = threadIdx.x;
  const int w = t >> 6, l = t & 63;
  const int rowBase = blockIdx.x * 64;

  {
    const uint4* src = (const uint4*)wsTg;
    uint4* dst = (uint4*)&wsT[0][0];
#pragma unroll
    for (int i = 0; i < 8; ++i) dst[t * 8 + i] = src[t * 8 + i];
  }

  f32x4 acc[4][2];
#pragma unroll
  for (int r = 0; r < 4; ++r)
#pragma unroll
    for (int cf = 0; cf < 2; ++cf) acc[r][cf] = (f32x4){0.f, 0.f, 0.f, 0.f};

  const int rr = t >> 2, cg = t & 3;
  const int grow_s = rowBase + rr;

  for (int kk0 = 0; kk0 < 128; kk0 += 32) {
    float4 v0 = make_float4(0.f, 0.f, 0.f, 0.f), v1 = v0;
    if (grow_s < NN) {
      v0 = *(const float4*)(&x[(size_t)grow_s * 128 + kk0 + cg * 8]);
      v1 = *(const float4*)(&x[(size_t)grow_s * 128 + kk0 + cg * 8 + 4]);
    }
    if (kk0) __syncthreads();
    {
      u32 p0 = bf16pair(v0.x, v0.y);
      u32 p1 = bf16pair(v0.z, v0.w);
      u32 p2 = bf16pair(v1.x, v1.y);
      u32 p3 = bf16pair(v1.z, v1.w);
      int sg = cg ^ ((rr >> 1) & 3);
      *(uint4*)(&xsb[rr][sg * 8]) = make_uint4(p0, p1, p2, p3);
    }
    __syncthreads();

    bf16x8 bfr[2];
#pragma unroll
    for (int cf = 0; cf < 2; ++cf) {
      int col = w * 32 + cf * 16 + (l & 15);
      int kg = (kk0 >> 3) + (l >> 4);
      bfr[cf] = *(const bf16x8*)(&wsT[col][(kg ^ (col & 7)) * 8]);
    }
#pragma unroll
    for (int r = 0; r < 4; ++r) {
      int row = r * 16 + (l & 15);
      int kg = l >> 4;
      bf16x8 afr = *(const bf16x8*)(&xsb[row][(kg ^ ((row >> 1) & 3)) * 8]);
#pragma unroll
      for (int cf = 0; cf < 2; ++cf)
        acc[r][cf] = __builtin_amdgcn_mfma_f32_16x16x32_bf16(afr, bfr[cf], acc[r][cf], 0, 0, 0);
    }
  }

  const int cl = l & 15;
  const int rq = l >> 4;
#pragma unroll
  for (int cf = 0; cf < 2; ++cf) {
    const int h = w * 2 + cf;
    const int gcol = w * 32 + cf * 16 + cl;
    const float as = a1[h * 32 + cl];
    const float ad = a1[h * 32 + 16 + cl];
#pragma unroll
    for (int r = 0; r < 4; ++r) {
#pragma unroll
      for (int i = 0; i < 4; ++i) {
        int grow = rowBase + r * 16 + rq * 4 + i;
        float wh = acc[r][cf][i];
        float ps = wh * as, pd = wh * ad;
        ps += __shfl_xor(ps, 1); ps += __shfl_xor(ps, 2);
        ps += __shfl_xor(ps, 4); ps += __shfl_xor(ps, 8);
        pd += __shfl_xor(pd, 1); pd += __shfl_xor(pd, 2);
        pd += __shfl_xor(pd, 4); pd += __shfl_xor(pd, 8);
        if (grow < NN) {
          Wh1b[(size_t)grow * 128 + gcol] = bf16rte(wh);
          if (cl == 0) { es1[grow * 8 + h] = ps; ed1[grow * 8 + h] = pd; }
        }
      }
    }
  }
}

// ---------------- Pass B: LDS-staged binning, 2-way replicated counters ----------------
__global__ __launch_bounds__(256) void k_bin(
    const int* __restrict__ src, const int* __restrict__ dst,
    int* __restrict__ cur, u32* __restrict__ ebuf)
{
  __shared__ int lcnt2[2][512];      // per wave-pair counters
  __shared__ int scn[512];           // totals -> inclusive scan
  __shared__ int goff[NBUCK];
  __shared__ u32 bin[4096];
  const int t = threadIdx.x;
  const int wp = (t >> 7) & 1;       // wave-pair 0/1
  const int e0 = blockIdx.x * 4096;

  lcnt2[0][t] = 0; lcnt2[0][t + 256] = 0;
  lcnt2[1][t] = 0; lcnt2[1][t + 256] = 0;
  __syncthreads();

  u32 ent[16]; short bb[16], lp[16];
#pragma unroll
  for (int i = 0; i < 16; ++i) {
    int e = e0 + i * 256 + t;
    if (e < NE) {
      int s = src[e], d = dst[e];
      int b = d >> BSH;
      ent[i] = (u32)s | ((u32)(d & 255) << 20);
      bb[i] = (short)b;
      lp[i] = (short)atomicAdd(&lcnt2[wp][b], 1);
    } else bb[i] = -1;
  }
  __syncthreads();
  scn[t] = lcnt2[0][t] + lcnt2[1][t];
  scn[t + 256] = lcnt2[0][t + 256] + lcnt2[1][t + 256];
  __syncthreads();
  for (int d = 1; d < 512; d <<= 1) {
    int v0 = (t >= d) ? scn[t - d] : 0;
    int v1 = (t + 256 >= d) ? scn[t + 256 - d] : 0;
    __syncthreads();
    scn[t] += v0; scn[t + 256] += v1;
    __syncthreads();
  }
  for (int b = t; b < NBUCK; b += 256) {
    int excl = b ? scn[b - 1] : 0;
    int cnt = scn[b] - excl;
    if (cnt) goff[b] = b * BCAP + atomicAdd(&cur[b], cnt);
  }
#pragma unroll
  for (int i = 0; i < 16; ++i) {
    if (bb[i] >= 0) {
      int b = bb[i];
      int excl = b ? scn[b - 1] : 0;
      int pos = excl + (wp ? lcnt2[0][b] : 0) + lp[i];
      bin[pos] = ent[i];
    }
  }
  __syncthreads();
  const int total = scn[NBUCK - 1];
  for (int i = t; i < total; i += 256) {
    int lo = 0, hi = NBUCK - 1;
    while (lo < hi) { int mid = (lo + hi) >> 1; if (scn[mid] > i) hi = mid; else lo = mid + 1; }
    int excl = lo ? scn[lo - 1] : 0;
    int g = goff[lo] + (i - excl);
    if (g < (lo + 1) * BCAP) ebuf[g] = bin[i];
  }
}

// ---------------- Pass C: per-bucket local counting sort ----------------
__global__ __launch_bounds__(256) void k_sort(
    const int* __restrict__ cur, u32* __restrict__ ebuf,
    int* __restrict__ offs, int* __restrict__ deg)
{
  __shared__ u32 ein[BCAP];
  __shared__ u32 eout[BCAP];
  __shared__ int nd[256];
  __shared__ int ncur[256];
  const int t = threadIdx.x;
  const int b = blockIdx.x;
  const int base = b * BCAP;
  int cnt = cur[b];
  if (cnt > BCAP) cnt = BCAP;
  const int nloc = min(256, NN - (b << BSH));

  for (int i = t; i < cnt; i += 256) ein[i] = ebuf[base + i];
  nd[t] = 0;
  __syncthreads();
  for (int i = t; i < cnt; i += 256) atomicAdd(&nd[ein[i] >> 20], 1);
  __syncthreads();
  const int myCnt = nd[t];
  for (int d = 1; d < 256; d <<= 1) {
    int v = (t >= d) ? nd[t - d] : 0;
    __syncthreads();
    nd[t] += v;
    __syncthreads();
  }
  const int excl = t ? nd[t - 1] : 0;
  ncur[t] = excl;
  if (t < nloc) {
    int node = (b << BSH) + t;
    offs[node] = base + excl;
    deg[node]  = myCnt;
  }
  __syncthreads();
  for (int i = t; i < cnt; i += 256) {
    u32 v = ein[i];
    int pos = atomicAdd(&ncur[v >> 20], 1);
    eout[pos] = v & 0xFFFFFu;
  }
  __syncthreads();
  for (int i = t; i < cnt; i += 256) ebuf[base + i] = eout[i];
}

// ---------------- Layer-1 aggregation: 4-deep MLP, pk_fma, h1 out bf16 ----------------
__global__ __launch_bounds__(256, 8) void k_agg1(
    const u16* __restrict__ Wh1b, const float* __restrict__ es1, const float* __restrict__ ed1,
    const int* __restrict__ offs, const int* __restrict__ deg, const int* __restrict__ csr,
    u16* __restrict__ h1b)
{
  const int wid = threadIdx.x >> 6;
  const int lane = threadIdx.x & 63;
  const int n = blockIdx.x * 4 + wid;
  if (n >= NN) return;
  const int s0 = offs[n];
  const int nE = deg[n];
  const int g = lane >> 4;
  const int db = lane & 15;
  const int h = db >> 1;
  const float edv = ed1[n * 8 + h];

  f32x2 acc[4];
#pragma unroll
  for (int i = 0; i < 4; ++i) { acc[i].x = 0.f; acc[i].y = 0.f; }
  float ssum = 0.f;

  int c0 = 0;
  for (; c0 + 16 <= nE; c0 += 16) {
    int ss[4];
#pragma unroll
    for (int q = 0; q < 4; ++q) ss[q] = csr[s0 + c0 + q * 4 + g];
    float zz[4];
#pragma unroll
    for (int q = 0; q < 4; ++q) {
      float z = es1[ss[q] * 8 + h] + edv;
      zz[q] = (z > 0.f) ? z : 0.2f * z;
    }
    uint4 raw[4];
#pragma unroll
    for (int q = 0; q < 4; ++q)
      raw[q] = *(const uint4*)(Wh1b + (size_t)ss[q] * 128 + db * 8);
#pragma unroll
    for (int q = 0; q < 4; ++q) {
      const float ww = __expf(zz[q]);
      ssum += ww;
      f32x2 w2; w2.x = ww; w2.y = ww;
      pkfma(acc[0], w2, raw[q].x);
      pkfma(acc[1], w2, raw[q].y);
      pkfma(acc[2], w2, raw[q].z);
      pkfma(acc[3], w2, raw[q].w);
    }
  }
  if (c0 < nE) {
    int jj[4], ss[4];
#pragma unroll
    for (int q = 0; q < 4; ++q) {
      jj[q] = c0 + q * 4 + g;
      ss[q] = csr[s0 + (jj[q] < nE ? jj[q] : 0)];
    }
    float zz[4];
#pragma unroll
    for (int q = 0; q < 4; ++q) {
      float z = es1[ss[q] * 8 + h] + edv;
      zz[q] = (z > 0.f) ? z : 0.2f * z;
    }
#pragma unroll
    for (int q = 0; q < 4; ++q) {
      if (jj[q] < nE) {
        const uint4 raw = *(const uint4*)(Wh1b + (size_t)ss[q] * 128 + db * 8);
        const float ww = __expf(zz[q]);
        ssum += ww;
        f32x2 w2; w2.x = ww; w2.y = ww;
        pkfma(acc[0], w2, raw.x);
        pkfma(acc[1], w2, raw.y);
        pkfma(acc[2], w2, raw.z);
        pkfma(acc[3], w2, raw.w);
      }
    }
  }
#pragma unroll
  for (int i = 0; i < 4; ++i) {
    acc[i].x += __shfl_xor(acc[i].x, 16);
    acc[i].y += __shfl_xor(acc[i].y, 16);
    acc[i].x += __shfl_xor(acc[i].x, 32);
    acc[i].y += __shfl_xor(acc[i].y, 32);
  }
  ssum += __shfl_xor(ssum, 16);
  ssum += __shfl_xor(ssum, 32);

  if (g == 0) {
    float inv = 1.f / (ssum + 1e-16f);
    float o[8];
#pragma unroll
    for (int i = 0; i < 4; ++i) {
      float v0 = acc[i].x * inv;
      float v1 = acc[i].y * inv;
      o[2 * i]     = (v0 > 0.f) ? v0 : expm1f(v0);
      o[2 * i + 1] = (v1 > 0.f) ? v1 : expm1f(v1);
    }
    u32 p0 = bf16pair(o[0], o[1]);
    u32 p1 = bf16pair(o[2], o[3]);
    u32 p2 = bf16pair(o[4], o[5]);
    u32 p3 = bf16pair(o[6], o[7]);
    *(uint4*)(h1b + (size_t)n * 128 + db * 8) = make_uint4(p0, p1, p2, p3);
  }
}

// ---------------- GEMM2: Wh2b(bf16, stride 48) = h1b(bf16) @ W2(128,40), fused es2/ed2 ----
__global__ __launch_bounds__(256) void k_gemm2(
    const u16* __restrict__ h1b, const float* __restrict__ W2,
    const float* __restrict__ a2,
    u16* __restrict__ Wh2b, float* __restrict__ es2, float* __restrict__ ed2)
{
  __shared__ float hs[128][36];
  __shared__ float w2s[32][40];
  const int t = threadIdx.x;
  const int rowBase = blockIdx.x * 128;
  const int cg = t & 3;
  const int rs = t >> 2;
  float acc[2][10];
#pragma unroll
  for (int r = 0; r < 2; ++r)
#pragma unroll
    for (int j = 0; j < 10; ++j) acc[r][j] = 0.f;

  for (int k0 = 0; k0 < 128; k0 += 32) {
#pragma unroll
    for (int p = 0; p < 2; ++p) {
      int idx = (p * 256 + t) * 8;
      int rr = idx >> 5, cc = idx & 31;
      int grow = rowBase + rr;
      uint4 hv = make_uint4(0u, 0u, 0u, 0u);
      if (grow < NN) hv = *(const uint4*)(h1b + (size_t)grow * 128 + k0 + cc);
      float2* dst = (float2*)&hs[rr][cc];
      dst[0] = make_float2(bflo(hv.x), bfhi(hv.x));
      dst[1] = make_float2(bflo(hv.y), bfhi(hv.y));
      dst[2] = make_float2(bflo(hv.z), bfhi(hv.z));
      dst[3] = make_float2(bflo(hv.w), bfhi(hv.w));
    }
#pragma unroll
    for (int p = 0; p < 5; ++p) {
      int idx = p * 256 + t;
      int kk = idx / 40, cc = idx % 40;
      w2s[kk][cc] = W2[(size_t)(k0 + kk) * 40 + cc];
    }
    __syncthreads();
#pragma unroll
    for (int k = 0; k < 32; ++k) {
      float a0 = hs[rs][k], a1v = hs[rs + 64][k];
#pragma unroll
      for (int j = 0; j < 10; ++j) {
        float b = w2s[k][cg * 10 + j];
        acc[0][j] = fmaf(a0, b, acc[0][j]);
        acc[1][j] = fmaf(a1v, b, acc[1][j]);
      }
    }
    __syncthreads();
  }
  float a2s[10], a2d[10];
#pragma unroll
  for (int j = 0; j < 10; ++j) {
    a2s[j] = a2[cg * 10 + j];
    a2d[j] = a2[40 + cg * 10 + j];
  }
#pragma unroll
  for (int rr = 0; rr < 2; ++rr) {
    int grow = rowBase + rs + rr * 64;
    float pes = 0.f, ped = 0.f;
#pragma unroll
    for (int j = 0; j < 10; ++j) {
      float v = acc[rr][j];
      pes = fmaf(v, a2s[j], pes);
      ped = fmaf(v, a2d[j], ped);
    }
    if (grow < NN) {
      u32* dst = (u32*)(Wh2b + (size_t)grow * 48 + cg * 10);
      dst[0] = bf16pair(acc[rr][0], acc[rr][1]);
      dst[1] = bf16pair(acc[rr][2], acc[rr][3]);
      dst[2] = bf16pair(acc[rr][4], acc[rr][5]);
      dst[3] = bf16pair(acc[rr][6], acc[rr][7]);
      dst[4] = bf16pair(acc[rr][8], acc[rr][9]);
    }
    pes += __shfl_xor(pes, 1); pes += __shfl_xor(pes, 2);
    ped += __shfl_xor(ped, 1); ped += __shfl_xor(ped, 2);
    if (cg == 0 && grow < NN) { es2[grow] = pes; ed2[grow] = ped; }
  }
}

// ---------------- Layer-2 aggregation: 6 edge-groups x 10 dim-lanes, h2 out bf16 ----------
__global__ __launch_bounds__(256, 8) void k_agg2(
    const u16* __restrict__ Wh2b, const float* __restrict__ es2, const float* __restrict__ ed2,
    const int* __restrict__ offs, const int* __restrict__ deg, const int* __restrict__ csr,
    u32* __restrict__ h2b)
{
  __shared__ float red[4][64][5];
  const int wid = threadIdx.x >> 6;
  const int lane = threadIdx.x & 63;
  const int n = blockIdx.x * 4 + wid;
  if (n >= NN) return;
  const int s0 = offs[n];
  const int nE = deg[n];
  const float edv = ed2[n];
  int e6 = lane / 10;
  const int r10 = lane - e6 * 10;
  const bool act = lane < 60;
  if (e6 > 5) e6 = 5;

  f32x2 acc0, acc1;
  acc0.x = acc0.y = acc1.x = acc1.y = 0.f;
  float ssum = 0.f;

  for (int c0 = 0; c0 < nE; c0 += 24) {
    int jj[4], ss[4];
#pragma unroll
    for (int q = 0; q < 4; ++q) {
      jj[q] = c0 + q * 6 + e6;
      ss[q] = csr[s0 + (jj[q] < nE ? jj[q] : 0)];
    }
    float zz[4];
#pragma unroll
    for (int q = 0; q < 4; ++q) {
      float z = es2[ss[q]] + edv;
      zz[q] = (z > 0.f) ? z : 0.2f * z;
    }
#pragma unroll
    for (int q = 0; q < 4; ++q) {
      if (act && jj[q] < nE) {
        const uint2 raw = *(const uint2*)(Wh2b + (size_t)ss[q] * 48 + r10 * 4);
        const float ww = __expf(zz[q]);
        ssum += ww;
        f32x2 w2; w2.x = ww; w2.y = ww;
        pkfma(acc0, w2, raw.x);
        pkfma(acc1, w2, raw.y);
      }
    }
  }
  red[wid][lane][0] = acc0.x; red[wid][lane][1] = acc0.y;
  red[wid][lane][2] = acc1.x; red[wid][lane][3] = acc1.y;
  red[wid][lane][4] = ssum;
  __builtin_amdgcn_wave_barrier();
  if (lane < 20) {
    const int rb = lane >> 1;           // dim quad 0..9
    const int eA = (lane & 1) * 2;      // dims eA, eA+1 within quad
    float aA = 0.f, aB = 0.f, sm = 0.f;
#pragma unroll
    for (int g = 0; g < 6; ++g) {
      aA += red[wid][g * 10 + rb][eA];
      aB += red[wid][g * 10 + rb][eA + 1];
      sm += red[wid][g * 10][4];
    }
    float inv = 1.f / (sm + 1e-16f);
    h2b[(size_t)n * 20 + lane] = bf16pair(aA * inv, aB * inv);
  }
}

// ---------------- Pooling (h2 in bf16) ----------------
__global__ __launch_bounds__(256) void k_pool1(
    const u32* __restrict__ h2b, const int* __restrict__ gstart,
    float* __restrict__ partial)
{
  __shared__ float lds[25][10][4];
  const int g = blockIdx.x >> 3;
  const int p = blockIdx.x & 7;
  const int t = threadIdx.x;
  const int s0 = gstart[g], s1 = gstart[g + 1];
  const int len = s1 - s0;
  const int chunk = (len + PB - 1) / PB;
  const int start = s0 + p * chunk;
  const int end = min(start + chunk, s1);
  const int slot = t / 10, q = t - slot * 10;
  float4 acc = make_float4(0.f, 0.f, 0.f, 0.f);
  if (slot < 25) {
    for (int n = start + slot; n < end; n += 25) {
      const uint2 v = *(const uint2*)(&h2b[(size_t)n * 20 + q * 2]);
      acc.x += bflo(v.x); acc.y += bfhi(v.x);
      acc.z += bflo(v.y); acc.w += bfhi(v.y);
    }
    lds[slot][q][0] = acc.x; lds[slot][q][1] = acc.y;
    lds[slot][q][2] = acc.z; lds[slot][q][3] = acc.w;
  }
  __syncthreads();
  if (t < 40) {
    const int qq = t >> 2, e = t & 3;
    float s = 0.f;
#pragma unroll
    for (int sl = 0; sl < 25; ++sl) s += lds[sl][qq][e];
    partial[(size_t)blockIdx.x * 40 + t] = s;
  }
}

__global__ void k_pool2(const float* __restrict__ partial, const int* __restrict__ gstart,
                        float* __restrict__ out)
{
  const int g = blockIdx.x;
  const int d = threadIdx.x;
  if (d >= 40) return;
  float s = 0.f;
#pragma unroll
  for (int p = 0; p < PB; ++p) s += partial[(size_t)(g * PB + p) * 40 + d];
  int cnt = gstart[g + 1] - gstart[g];
  if (cnt < 1) cnt = 1;
  out[g * 40 + d] = s / (float)cnt;
}

extern "C" void kernel_launch(void* const* d_in, const int* in_sizes, int n_in,
                              void* d_out, int out_size, void* d_ws, size_t ws_size,
                              hipStream_t stream)
{
  const float* x   = (const float*)d_in[0];
  const float* W1  = (const float*)d_in[1];
  const float* a1  = (const float*)d_in[2];
  const float* W2  = (const float*)d_in[3];
  const float* a2  = (const float*)d_in[4];
  const int* eidx  = (const int*)d_in[5];
  const int* batch = (const int*)d_in[6];
  float* out = (float*)d_out;

  char* ws = (char*)d_ws;
  u16*   Wh1b = (u16*)(ws + 0);              // 25,600,000 B
  u16*   Wh2b = (u16*)(ws + 0);              //  9,600,000 B (reuse after agg1)
  u32*   h2b  = (u32*)(ws + 9600000);        //  8,000,000 B (reuse; bf16 packed)
  u16*   h1b  = (u16*)(ws + 25600000);       // 25,600,000 B
  float* es1  = (float*)(ws + 51200000);     //  3,200,000
  float* ed1  = (float*)(ws + 54400000);     //  3,200,000
  float* es2  = (float*)(ws + 57600000);     //    400,000
  float* ed2  = (float*)(ws + 58000000);     //    400,000
  u32*   ebuf = (u32*)(ws + 58400000);       //  8,007,680 (NBUCK*BCAP*4) -> becomes csr
  int*   offs = (int*)(ws + 66407680);       //    400,000
  int*   deg  = (int*)(ws + 66807680);       //    400,000
  int*   cur  = (int*)(ws + 67207680);       //      2,048
  int*   gstart = (int*)(ws + 67209728);     //        512
  float* partial = (float*)(ws + 67210240);  //     81,920
  u16*   wsTg = (u16*)(ws + 67292160);       //     32,768 (bf16 swizzled W1^T)
  // total ~67.3 MB

  const int* esrc = eidx;
  const int* edst = eidx + NE;

  k_prep<<<65, 256, 0, stream>>>(W1, wsTg, batch, gstart, cur);
  k_gemm1<<<(NN + 63) / 64, 256, 0, stream>>>(x, wsTg, a1, Wh1b, es1, ed1);
  k_bin<<<(NE + 4095) / 4096, 256, 0, stream>>>(esrc, edst, cur, ebuf);
  k_sort<<<NBUCK, 256, 0, stream>>>(cur, ebuf, offs, deg);
  k_agg1<<<(NN + 3) / 4, 256, 0, stream>>>(Wh1b, es1, ed1, offs, deg, (const int*)ebuf, h1b);
  k_gemm2<<<(NN + 127) / 128, 256, 0, stream>>>(h1b, W2, a2, Wh2b, es2, ed2);
  k_agg2<<<(NN + 3) / 4, 256, 0, stream>>>(Wh2b, es2, ed2, offs, deg, (const int*)ebuf, h2b);
  k_pool1<<<NG * PB, 256, 0, stream>>>(h2b, gstart, partial);
  k_pool2<<<NG, 64, 0, stream>>>(partial, gstart, out);
}

// Round 12
// 245.122 us; speedup vs baseline: 1.5833x; 1.0223x over previous
//
#include <hip/hip_runtime.h>
#include <hip/hip_bf16.h>

typedef unsigned short u16;
typedef unsigned int   u32;
typedef float f32x2 __attribute__((ext_vector_type(2)));
typedef float f32x4 __attribute__((ext_vector_type(4)));
typedef short bf16x8 __attribute__((ext_vector_type(8)));

static constexpr int NN = 100000;   // nodes
static constexpr int NE = 1600000;  // edges
static constexpr int NG = 64;       // graphs

static constexpr int BSH   = 8;     // nodes per bucket = 256
static constexpr int NBUCK = 391;   // ceil(NN / 256)
static constexpr int BCAP  = 5120;  // bucket capacity (mean 4096, sd ~64)
static constexpr int PB    = 8;     // pooling partial-blocks per graph

// RTNE f32->bf16
__device__ __forceinline__ u16 bf16rte(float a) {
  u32 u = __builtin_bit_cast(u32, a);
  u = (u + 0x7FFFu + ((u >> 16) & 1u)) >> 16;
  return (u16)u;
}
__device__ __forceinline__ u32 bf16pair(float a, float b) {
  return (u32)bf16rte(a) | ((u32)bf16rte(b) << 16);
}
__device__ __forceinline__ float bflo(u32 u) { return __builtin_bit_cast(float, u << 16); }
__device__ __forceinline__ float bfhi(u32 u) { return __builtin_bit_cast(float, u & 0xFFFF0000u); }

// packed dual-FMA: a.lo += w.lo*bflo(u); a.hi += w.hi*bfhi(u)
__device__ __forceinline__ void pkfma(f32x2& a, f32x2 w2, u32 u) {
  f32x2 v;
  v.x = bflo(u); v.y = bfhi(u);
  asm("v_pk_fma_f32 %0, %1, %2, %0" : "+v"(a) : "v"(w2), "v"(v));
}

// ---- prep: W1 -> bf16 swizzled (blocks 0..63) | gbounds + cur-zero (block 64) ----
__global__ void k_prep(const float* __restrict__ W1, u16* __restrict__ wsTg,
                       const int* __restrict__ batch, int* __restrict__ gstart,
                       int* __restrict__ cur) {
  const int bid = blockIdx.x;
  if (bid < 64) {
    int idx = bid * 256 + threadIdx.x;   // 64*256 = 16384 = all of W1
    int k = idx >> 7, c = idx & 127;
    wsTg[c * 128 + (((k >> 3) ^ (c & 7)) << 3) + (k & 7)] = bf16rte(W1[idx]);
  } else {
    int t = threadIdx.x;
    for (int i = t; i < NBUCK; i += 256) cur[i] = 0;
    if (t <= NG) {
      int lo = 0, hi = NN;
      while (lo < hi) { int mid = (lo + hi) >> 1; if (batch[mid] < t) lo = mid + 1; else hi = mid; }
      gstart[t] = lo;
    }
  }
}

// ---------------- GEMM1 (MFMA bf16): Wh1b = x @ W1, fused es1/ed1 ----------------
__global__ __launch_bounds__(256) void k_gemm1(
    const float* __restrict__ x, const u16* __restrict__ wsTg, const float* __restrict__ a1,
    u16* __restrict__ Wh1b, float* __restrict__ es1, float* __restrict__ ed1)
{
  __shared__ u16 wsT[128][128];   // [col][k], kg' = kg ^ (col&7)  (32 KB)
  __shared__ u16 xsb[64][32];     // [row][k-in-step], kg' = kg ^ ((row>>1)&3)  (4 KB)
  const int t = threadIdx.x;
  const int w = t >> 6, l = t & 63;
  const int rowBase = blockIdx.x * 64;

  {
    const uint4* src = (const uint4*)wsTg;
    uint4* dst = (uint4*)&wsT[0][0];
#pragma unroll
    for (int i = 0; i < 8; ++i) dst[t * 8 + i] = src[t * 8 + i];
  }

  f32x4 acc[4][2];
#pragma unroll
  for (int r = 0; r < 4; ++r)
#pragma unroll
    for (int cf = 0; cf < 2; ++cf) acc[r][cf] = (f32x4){0.f, 0.f, 0.f, 0.f};

  const int rr = t >> 2, cg = t & 3;
  const int grow_s = rowBase + rr;

  for (int kk0 = 0; kk0 < 128; kk0 += 32) {
    float4 v0 = make_float4(0.f, 0.f, 0.f, 0.f), v1 = v0;
    if (grow_s < NN) {
      v0 = *(const float4*)(&x[(size_t)grow_s * 128 + kk0 + cg * 8]);
      v1 = *(const float4*)(&x[(size_t)grow_s * 128 + kk0 + cg * 8 + 4]);
    }
    if (kk0) __syncthreads();
    {
      u32 p0 = bf16pair(v0.x, v0.y);
      u32 p1 = bf16pair(v0.z, v0.w);
      u32 p2 = bf16pair(v1.x, v1.y);
      u32 p3 = bf16pair(v1.z, v1.w);
      int sg = cg ^ ((rr >> 1) & 3);
      *(uint4*)(&xsb[rr][sg * 8]) = make_uint4(p0, p1, p2, p3);
    }
    __syncthreads();

    bf16x8 bfr[2];
#pragma unroll
    for (int cf = 0; cf < 2; ++cf) {
      int col = w * 32 + cf * 16 + (l & 15);
      int kg = (kk0 >> 3) + (l >> 4);
      bfr[cf] = *(const bf16x8*)(&wsT[col][(kg ^ (col & 7)) * 8]);
    }
#pragma unroll
    for (int r = 0; r < 4; ++r) {
      int row = r * 16 + (l & 15);
      int kg = l >> 4;
      bf16x8 afr = *(const bf16x8*)(&xsb[row][(kg ^ ((row >> 1) & 3)) * 8]);
#pragma unroll
      for (int cf = 0; cf < 2; ++cf)
        acc[r][cf] = __builtin_amdgcn_mfma_f32_16x16x32_bf16(afr, bfr[cf], acc[r][cf], 0, 0, 0);
    }
  }

  const int cl = l & 15;
  const int rq = l >> 4;
#pragma unroll
  for (int cf = 0; cf < 2; ++cf) {
    const int h = w * 2 + cf;
    const int gcol = w * 32 + cf * 16 + cl;
    const float as = a1[h * 32 + cl];
    const float ad = a1[h * 32 + 16 + cl];
#pragma unroll
    for (int r = 0; r < 4; ++r) {
#pragma unroll
      for (int i = 0; i < 4; ++i) {
        int grow = rowBase + r * 16 + rq * 4 + i;
        float wh = acc[r][cf][i];
        float ps = wh * as, pd = wh * ad;
        ps += __shfl_xor(ps, 1); ps += __shfl_xor(ps, 2);
        ps += __shfl_xor(ps, 4); ps += __shfl_xor(ps, 8);
        pd += __shfl_xor(pd, 1); pd += __shfl_xor(pd, 2);
        pd += __shfl_xor(pd, 4); pd += __shfl_xor(pd, 8);
        if (grow < NN) {
          Wh1b[(size_t)grow * 128 + gcol] = bf16rte(wh);
          if (cl == 0) { es1[grow * 8 + h] = ps; ed1[grow * 8 + h] = pd; }
        }
      }
    }
  }
}

// ---- Pass B: binning, 2-way replicated counters, DIRECT global scatter (no LDS stage) ----
__global__ __launch_bounds__(256) void k_bin(
    const int* __restrict__ src, const int* __restrict__ dst,
    int* __restrict__ cur, u32* __restrict__ ebuf)
{
  __shared__ int lcnt2[2][512];      // per wave-pair counters (kept intact through scatter)
  __shared__ int scn[512];           // totals -> inclusive scan (for reservation only)
  __shared__ int goff[NBUCK];
  const int t = threadIdx.x;
  const int wp = (t >> 7) & 1;       // wave-pair 0/1
  const int e0 = blockIdx.x * 4096;

  lcnt2[0][t] = 0; lcnt2[0][t + 256] = 0;
  lcnt2[1][t] = 0; lcnt2[1][t + 256] = 0;
  __syncthreads();

  u32 ent[16]; short bb[16], lp[16];
#pragma unroll
  for (int i = 0; i < 16; ++i) {
    int e = e0 + i * 256 + t;
    if (e < NE) {
      int s = src[e], d = dst[e];
      int b = d >> BSH;
      ent[i] = (u32)s | ((u32)(d & 255) << 20);
      bb[i] = (short)b;
      lp[i] = (short)atomicAdd(&lcnt2[wp][b], 1);
    } else bb[i] = -1;
  }
  __syncthreads();
  scn[t] = lcnt2[0][t] + lcnt2[1][t];
  scn[t + 256] = lcnt2[0][t + 256] + lcnt2[1][t + 256];
  __syncthreads();
  for (int d = 1; d < 512; d <<= 1) {
    int v0 = (t >= d) ? scn[t - d] : 0;
    int v1 = (t + 256 >= d) ? scn[t + 256 - d] : 0;
    __syncthreads();
    scn[t] += v0; scn[t + 256] += v1;
    __syncthreads();
  }
  for (int b = t; b < NBUCK; b += 256) {
    int excl = b ? scn[b - 1] : 0;
    int cnt = scn[b] - excl;
    if (cnt) goff[b] = b * BCAP + atomicAdd(&cur[b], cnt);
  }
  __syncthreads();
  // direct scatter: position known in closed form; order identical to staged flush
#pragma unroll
  for (int i = 0; i < 16; ++i) {
    if (bb[i] >= 0) {
      int b = bb[i];
      int g = goff[b] + (wp ? lcnt2[0][b] : 0) + lp[i];
      if (g < (b + 1) * BCAP) ebuf[g] = ent[i];
    }
  }
}

// ---------------- Pass C: per-bucket local counting sort ----------------
__global__ __launch_bounds__(256) void k_sort(
    const int* __restrict__ cur, u32* __restrict__ ebuf,
    int* __restrict__ offs, int* __restrict__ deg)
{
  __shared__ u32 ein[BCAP];
  __shared__ u32 eout[BCAP];
  __shared__ int nd[256];
  __shared__ int ncur[256];
  const int t = threadIdx.x;
  const int b = blockIdx.x;
  const int base = b * BCAP;
  int cnt = cur[b];
  if (cnt > BCAP) cnt = BCAP;
  const int nloc = min(256, NN - (b << BSH));

  for (int i = t; i < cnt; i += 256) ein[i] = ebuf[base + i];
  nd[t] = 0;
  __syncthreads();
  for (int i = t; i < cnt; i += 256) atomicAdd(&nd[ein[i] >> 20], 1);
  __syncthreads();
  const int myCnt = nd[t];
  for (int d = 1; d < 256; d <<= 1) {
    int v = (t >= d) ? nd[t - d] : 0;
    __syncthreads();
    nd[t] += v;
    __syncthreads();
  }
  const int excl = t ? nd[t - 1] : 0;
  ncur[t] = excl;
  if (t < nloc) {
    int node = (b << BSH) + t;
    offs[node] = base + excl;
    deg[node]  = myCnt;
  }
  __syncthreads();
  for (int i = t; i < cnt; i += 256) {
    u32 v = ein[i];
    int pos = atomicAdd(&ncur[v >> 20], 1);
    eout[pos] = v & 0xFFFFFu;
  }
  __syncthreads();
  for (int i = t; i < cnt; i += 256) ebuf[base + i] = eout[i];
}

// ---------------- Layer-1 aggregation: 4-deep MLP, pk_fma, h1 out bf16 ----------------
__global__ __launch_bounds__(256, 8) void k_agg1(
    const u16* __restrict__ Wh1b, const float* __restrict__ es1, const float* __restrict__ ed1,
    const int* __restrict__ offs, const int* __restrict__ deg, const int* __restrict__ csr,
    u16* __restrict__ h1b)
{
  const int wid = threadIdx.x >> 6;
  const int lane = threadIdx.x & 63;
  const int n = blockIdx.x * 4 + wid;
  if (n >= NN) return;
  const int s0 = offs[n];
  const int nE = deg[n];
  const int g = lane >> 4;
  const int db = lane & 15;
  const int h = db >> 1;
  const float edv = ed1[n * 8 + h];

  f32x2 acc[4];
#pragma unroll
  for (int i = 0; i < 4; ++i) { acc[i].x = 0.f; acc[i].y = 0.f; }
  float ssum = 0.f;

  int c0 = 0;
  for (; c0 + 16 <= nE; c0 += 16) {
    int ss[4];
#pragma unroll
    for (int q = 0; q < 4; ++q) ss[q] = csr[s0 + c0 + q * 4 + g];
    float zz[4];
#pragma unroll
    for (int q = 0; q < 4; ++q) {
      float z = es1[ss[q] * 8 + h] + edv;
      zz[q] = (z > 0.f) ? z : 0.2f * z;
    }
    uint4 raw[4];
#pragma unroll
    for (int q = 0; q < 4; ++q)
      raw[q] = *(const uint4*)(Wh1b + (size_t)ss[q] * 128 + db * 8);
#pragma unroll
    for (int q = 0; q < 4; ++q) {
      const float ww = __expf(zz[q]);
      ssum += ww;
      f32x2 w2; w2.x = ww; w2.y = ww;
      pkfma(acc[0], w2, raw[q].x);
      pkfma(acc[1], w2, raw[q].y);
      pkfma(acc[2], w2, raw[q].z);
      pkfma(acc[3], w2, raw[q].w);
    }
  }
  if (c0 < nE) {
    int jj[4], ss[4];
#pragma unroll
    for (int q = 0; q < 4; ++q) {
      jj[q] = c0 + q * 4 + g;
      ss[q] = csr[s0 + (jj[q] < nE ? jj[q] : 0)];
    }
    float zz[4];
#pragma unroll
    for (int q = 0; q < 4; ++q) {
      float z = es1[ss[q] * 8 + h] + edv;
      zz[q] = (z > 0.f) ? z : 0.2f * z;
    }
#pragma unroll
    for (int q = 0; q < 4; ++q) {
      if (jj[q] < nE) {
        const uint4 raw = *(const uint4*)(Wh1b + (size_t)ss[q] * 128 + db * 8);
        const float ww = __expf(zz[q]);
        ssum += ww;
        f32x2 w2; w2.x = ww; w2.y = ww;
        pkfma(acc[0], w2, raw.x);
        pkfma(acc[1], w2, raw.y);
        pkfma(acc[2], w2, raw.z);
        pkfma(acc[3], w2, raw.w);
      }
    }
  }
#pragma unroll
  for (int i = 0; i < 4; ++i) {
    acc[i].x += __shfl_xor(acc[i].x, 16);
    acc[i].y += __shfl_xor(acc[i].y, 16);
    acc[i].x += __shfl_xor(acc[i].x, 32);
    acc[i].y += __shfl_xor(acc[i].y, 32);
  }
  ssum += __shfl_xor(ssum, 16);
  ssum += __shfl_xor(ssum, 32);

  if (g == 0) {
    float inv = 1.f / (ssum + 1e-16f);
    float o[8];
#pragma unroll
    for (int i = 0; i < 4; ++i) {
      float v0 = acc[i].x * inv;
      float v1 = acc[i].y * inv;
      o[2 * i]     = (v0 > 0.f) ? v0 : expm1f(v0);
      o[2 * i + 1] = (v1 > 0.f) ? v1 : expm1f(v1);
    }
    u32 p0 = bf16pair(o[0], o[1]);
    u32 p1 = bf16pair(o[2], o[3]);
    u32 p2 = bf16pair(o[4], o[5]);
    u32 p3 = bf16pair(o[6], o[7]);
    *(uint4*)(h1b + (size_t)n * 128 + db * 8) = make_uint4(p0, p1, p2, p3);
  }
}

// ---------------- GEMM2: Wh2b(bf16, stride 48) = h1b(bf16) @ W2(128,40), fused es2/ed2 ----
__global__ __launch_bounds__(256) void k_gemm2(
    const u16* __restrict__ h1b, const float* __restrict__ W2,
    const float* __restrict__ a2,
    u16* __restrict__ Wh2b, float* __restrict__ es2, float* __restrict__ ed2)
{
  __shared__ float hs[128][36];
  __shared__ float w2s[32][40];
  const int t = threadIdx.x;
  const int rowBase = blockIdx.x * 128;
  const int cg = t & 3;
  const int rs = t >> 2;
  float acc[2][10];
#pragma unroll
  for (int r = 0; r < 2; ++r)
#pragma unroll
    for (int j = 0; j < 10; ++j) acc[r][j] = 0.f;

  for (int k0 = 0; k0 < 128; k0 += 32) {
#pragma unroll
    for (int p = 0; p < 2; ++p) {
      int idx = (p * 256 + t) * 8;
      int rr = idx >> 5, cc = idx & 31;
      int grow = rowBase + rr;
      uint4 hv = make_uint4(0u, 0u, 0u, 0u);
      if (grow < NN) hv = *(const uint4*)(h1b + (size_t)grow * 128 + k0 + cc);
      float2* dst = (float2*)&hs[rr][cc];
      dst[0] = make_float2(bflo(hv.x), bfhi(hv.x));
      dst[1] = make_float2(bflo(hv.y), bfhi(hv.y));
      dst[2] = make_float2(bflo(hv.z), bfhi(hv.z));
      dst[3] = make_float2(bflo(hv.w), bfhi(hv.w));
    }
#pragma unroll
    for (int p = 0; p < 5; ++p) {
      int idx = p * 256 + t;
      int kk = idx / 40, cc = idx % 40;
      w2s[kk][cc] = W2[(size_t)(k0 + kk) * 40 + cc];
    }
    __syncthreads();
#pragma unroll
    for (int k = 0; k < 32; ++k) {
      float a0 = hs[rs][k], a1v = hs[rs + 64][k];
#pragma unroll
      for (int j = 0; j < 10; ++j) {
        float b = w2s[k][cg * 10 + j];
        acc[0][j] = fmaf(a0, b, acc[0][j]);
        acc[1][j] = fmaf(a1v, b, acc[1][j]);
      }
    }
    __syncthreads();
  }
  float a2s[10], a2d[10];
#pragma unroll
  for (int j = 0; j < 10; ++j) {
    a2s[j] = a2[cg * 10 + j];
    a2d[j] = a2[40 + cg * 10 + j];
  }
#pragma unroll
  for (int rr = 0; rr < 2; ++rr) {
    int grow = rowBase + rs + rr * 64;
    float pes = 0.f, ped = 0.f;
#pragma unroll
    for (int j = 0; j < 10; ++j) {
      float v = acc[rr][j];
      pes = fmaf(v, a2s[j], pes);
      ped = fmaf(v, a2d[j], ped);
    }
    if (grow < NN) {
      u32* dst = (u32*)(Wh2b + (size_t)grow * 48 + cg * 10);
      dst[0] = bf16pair(acc[rr][0], acc[rr][1]);
      dst[1] = bf16pair(acc[rr][2], acc[rr][3]);
      dst[2] = bf16pair(acc[rr][4], acc[rr][5]);
      dst[3] = bf16pair(acc[rr][6], acc[rr][7]);
      dst[4] = bf16pair(acc[rr][8], acc[rr][9]);
    }
    pes += __shfl_xor(pes, 1); pes += __shfl_xor(pes, 2);
    ped += __shfl_xor(ped, 1); ped += __shfl_xor(ped, 2);
    if (cg == 0 && grow < NN) { es2[grow] = pes; ed2[grow] = ped; }
  }
}

// ---------------- Layer-2 aggregation: 6 edge-groups x 10 dim-lanes, h2 out bf16 ----------
__global__ __launch_bounds__(256, 8) void k_agg2(
    const u16* __restrict__ Wh2b, const float* __restrict__ es2, const float* __restrict__ ed2,
    const int* __restrict__ offs, const int* __restrict__ deg, const int* __restrict__ csr,
    u32* __restrict__ h2b)
{
  __shared__ float red[4][64][5];
  const int wid = threadIdx.x >> 6;
  const int lane = threadIdx.x & 63;
  const int n = blockIdx.x * 4 + wid;
  if (n >= NN) return;
  const int s0 = offs[n];
  const int nE = deg[n];
  const float edv = ed2[n];
  int e6 = lane / 10;
  const int r10 = lane - e6 * 10;
  const bool act = lane < 60;
  if (e6 > 5) e6 = 5;

  f32x2 acc0, acc1;
  acc0.x = acc0.y = acc1.x = acc1.y = 0.f;
  float ssum = 0.f;

  for (int c0 = 0; c0 < nE; c0 += 24) {
    int jj[4], ss[4];
#pragma unroll
    for (int q = 0; q < 4; ++q) {
      jj[q] = c0 + q * 6 + e6;
      ss[q] = csr[s0 + (jj[q] < nE ? jj[q] : 0)];
    }
    float zz[4];
#pragma unroll
    for (int q = 0; q < 4; ++q) {
      float z = es2[ss[q]] + edv;
      zz[q] = (z > 0.f) ? z : 0.2f * z;
    }
#pragma unroll
    for (int q = 0; q < 4; ++q) {
      if (act && jj[q] < nE) {
        const uint2 raw = *(const uint2*)(Wh2b + (size_t)ss[q] * 48 + r10 * 4);
        const float ww = __expf(zz[q]);
        ssum += ww;
        f32x2 w2; w2.x = ww; w2.y = ww;
        pkfma(acc0, w2, raw.x);
        pkfma(acc1, w2, raw.y);
      }
    }
  }
  red[wid][lane][0] = acc0.x; red[wid][lane][1] = acc0.y;
  red[wid][lane][2] = acc1.x; red[wid][lane][3] = acc1.y;
  red[wid][lane][4] = ssum;
  __builtin_amdgcn_wave_barrier();
  if (lane < 20) {
    const int rb = lane >> 1;           // dim quad 0..9
    const int eA = (lane & 1) * 2;      // dims eA, eA+1 within quad
    float aA = 0.f, aB = 0.f, sm = 0.f;
#pragma unroll
    for (int g = 0; g < 6; ++g) {
      aA += red[wid][g * 10 + rb][eA];
      aB += red[wid][g * 10 + rb][eA + 1];
      sm += red[wid][g * 10][4];
    }
    float inv = 1.f / (sm + 1e-16f);
    h2b[(size_t)n * 20 + lane] = bf16pair(aA * inv, aB * inv);
  }
}

// ---------------- Pooling (h2 in bf16) ----------------
__global__ __launch_bounds__(256) void k_pool1(
    const u32* __restrict__ h2b, const int* __restrict__ gstart,
    float* __restrict__ partial)
{
  __shared__ float lds[25][10][4];
  const int g = blockIdx.x >> 3;
  const int p = blockIdx.x & 7;
  const int t = threadIdx.x;
  const int s0 = gstart[g], s1 = gstart[g + 1];
  const int len = s1 - s0;
  const int chunk = (len + PB - 1) / PB;
  const int start = s0 + p * chunk;
  const int end = min(start + chunk, s1);
  const int slot = t / 10, q = t - slot * 10;
  float4 acc = make_float4(0.f, 0.f, 0.f, 0.f);
  if (slot < 25) {
    for (int n = start + slot; n < end; n += 25) {
      const uint2 v = *(const uint2*)(&h2b[(size_t)n * 20 + q * 2]);
      acc.x += bflo(v.x); acc.y += bfhi(v.x);
      acc.z += bflo(v.y); acc.w += bfhi(v.y);
    }
    lds[slot][q][0] = acc.x; lds[slot][q][1] = acc.y;
    lds[slot][q][2] = acc.z; lds[slot][q][3] = acc.w;
  }
  __syncthreads();
  if (t < 40) {
    const int qq = t >> 2, e = t & 3;
    float s = 0.f;
#pragma unroll
    for (int sl = 0; sl < 25; ++sl) s += lds[sl][qq][e];
    partial[(size_t)blockIdx.x * 40 + t] = s;
  }
}

__global__ void k_pool2(const float* __restrict__ partial, const int* __restrict__ gstart,
                        float* __restrict__ out)
{
  const int g = blockIdx.x;
  const int d = threadIdx.x;
  if (d >= 40) return;
  float s = 0.f;
#pragma unroll
  for (int p = 0; p < PB; ++p) s += partial[(size_t)(g * PB + p) * 40 + d];
  int cnt = gstart[g + 1] - gstart[g];
  if (cnt < 1) cnt = 1;
  out[g * 40 + d] = s / (float)cnt;
}

extern "C" void kernel_launch(void* const* d_in, const int* in_sizes, int n_in,
                              void* d_out, int out_size, void* d_ws, size_t ws_size,
                              hipStream_t stream)
{
  const float* x   = (const float*)d_in[0];
  const float* W1  = (const float*)d_in[1];
  const float* a1  = (const float*)d_in[2];
  const float* W2  = (const float*)d_in[3];
  const float* a2  = (const float*)d_in[4];
  const int* eidx  = (const int*)d_in[5];
  const int* batch = (const int*)d_in[6];
  float* out = (float*)d_out;

  char* ws = (char*)d_ws;
  u16*   Wh1b = (u16*)(ws + 0);              // 25,600,000 B
  u16*   Wh2b = (u16*)(ws + 0);              //  9,600,000 B (reuse after agg1)
  u32*   h2b  = (u32*)(ws + 9600000);        //  8,000,000 B (reuse; bf16 packed)
  u16*   h1b  = (u16*)(ws + 25600000);       // 25,600,000 B
  float* es1  = (float*)(ws + 51200000);     //  3,200,000
  float* ed1  = (float*)(ws + 54400000);     //  3,200,000
  float* es2  = (float*)(ws + 57600000);     //    400,000
  float* ed2  = (float*)(ws + 58000000);     //    400,000
  u32*   ebuf = (u32*)(ws + 58400000);       //  8,007,680 (NBUCK*BCAP*4) -> becomes csr
  int*   offs = (int*)(ws + 66407680);       //    400,000
  int*   deg  = (int*)(ws + 66807680);       //    400,000
  int*   cur  = (int*)(ws + 67207680);       //      2,048
  int*   gstart = (int*)(ws + 67209728);     //        512
  float* partial = (float*)(ws + 67210240);  //     81,920
  u16*   wsTg = (u16*)(ws + 67292160);       //     32,768 (bf16 swizzled W1^T)
  // total ~67.3 MB

  const int* esrc = eidx;
  const int* edst = eidx + NE;

  k_prep<<<65, 256, 0, stream>>>(W1, wsTg, batch, gstart, cur);
  k_gemm1<<<(NN + 63) / 64, 256, 0, stream>>>(x, wsTg, a1, Wh1b, es1, ed1);
  k_bin<<<(NE + 4095) / 4096, 256, 0, stream>>>(esrc, edst, cur, ebuf);
  k_sort<<<NBUCK, 256, 0, stream>>>(cur, ebuf, offs, deg);
  k_agg1<<<(NN + 3) / 4, 256, 0, stream>>>(Wh1b, es1, ed1, offs, deg, (const int*)ebuf, h1b);
  k_gemm2<<<(NN + 127) / 128, 256, 0, stream>>>(h1b, W2, a2, Wh2b, es2, ed2);
  k_agg2<<<(NN + 3) / 4, 256, 0, stream>>>(Wh2b, es2, ed2, offs, deg, (const int*)ebuf, h2b);
  k_pool1<<<NG * PB, 256, 0, stream>>>(h2b, gstart, partial);
  k_pool2<<<NG, 64, 0, stream>>>(partial, gstart, out);
}

// Round 13
// 238.268 us; speedup vs baseline: 1.6288x; 1.0288x over previous
//
#include <hip/hip_runtime.h>
#include <hip/hip_bf16.h>

typedef unsigned short u16;
typedef unsigned int   u32;
typedef float f32x2 __attribute__((ext_vector_type(2)));
typedef float f32x4 __attribute__((ext_vector_type(4)));
typedef short bf16x8 __attribute__((ext_vector_type(8)));

static constexpr int NN = 100000;   // nodes
static constexpr int NE = 1600000;  // edges
static constexpr int NG = 64;       // graphs

static constexpr int BSH   = 8;     // nodes per bucket = 256
static constexpr int NBUCK = 391;   // ceil(NN / 256)
static constexpr int BCAP  = 5120;  // bucket capacity (mean 4096, sd ~64)
static constexpr int PB    = 8;     // pooling partial-blocks per graph

// RTNE f32->bf16
__device__ __forceinline__ u16 bf16rte(float a) {
  u32 u = __builtin_bit_cast(u32, a);
  u = (u + 0x7FFFu + ((u >> 16) & 1u)) >> 16;
  return (u16)u;
}
__device__ __forceinline__ u32 bf16pair(float a, float b) {
  return (u32)bf16rte(a) | ((u32)bf16rte(b) << 16);
}
__device__ __forceinline__ float bflo(u32 u) { return __builtin_bit_cast(float, u << 16); }
__device__ __forceinline__ float bfhi(u32 u) { return __builtin_bit_cast(float, u & 0xFFFF0000u); }

// packed dual-FMA: a.lo += w.lo*bflo(u); a.hi += w.hi*bfhi(u)
__device__ __forceinline__ void pkfma(f32x2& a, f32x2 w2, u32 u) {
  f32x2 v;
  v.x = bflo(u); v.y = bfhi(u);
  asm("v_pk_fma_f32 %0, %1, %2, %0" : "+v"(a) : "v"(w2), "v"(v));
}

// ---- prep: W1 swizzled (0..63) | gbounds + cur-zero (64) | W2 -> bf16 pairs (65) ----
// wsW2 layout: [pc 0..19][d 0..127] u32, pc = col-pair (cols 2pc, 2pc+1)
__global__ void k_prep(const float* __restrict__ W1, u16* __restrict__ wsTg,
                       const int* __restrict__ batch, int* __restrict__ gstart,
                       int* __restrict__ cur,
                       const float* __restrict__ W2, u32* __restrict__ wsW2) {
  const int bid = blockIdx.x;
  if (bid < 64) {
    int idx = bid * 256 + threadIdx.x;   // 64*256 = 16384 = all of W1
    int k = idx >> 7, c = idx & 127;
    wsTg[c * 128 + (((k >> 3) ^ (c & 7)) << 3) + (k & 7)] = bf16rte(W1[idx]);
  } else if (bid == 64) {
    int t = threadIdx.x;
    for (int i = t; i < NBUCK; i += 256) cur[i] = 0;
    if (t <= NG) {
      int lo = 0, hi = NN;
      while (lo < hi) { int mid = (lo + hi) >> 1; if (batch[mid] < t) lo = mid + 1; else hi = mid; }
      gstart[t] = lo;
    }
  } else {
    const int t = threadIdx.x;
#pragma unroll
    for (int i = 0; i < 10; ++i) {
      int idx = t * 10 + i;            // 2560 entries
      int pc = idx >> 7, d = idx & 127;
      wsW2[idx] = bf16pair(W2[d * 40 + pc * 2], W2[d * 40 + pc * 2 + 1]);
    }
  }
}

// ---------------- GEMM1 (MFMA bf16): Wh1b = x @ W1, fused es1/ed1 ----------------
__global__ __launch_bounds__(256) void k_gemm1(
    const float* __restrict__ x, const u16* __restrict__ wsTg, const float* __restrict__ a1,
    u16* __restrict__ Wh1b, float* __restrict__ es1, float* __restrict__ ed1)
{
  __shared__ u16 wsT[128][128];   // [col][k], kg' = kg ^ (col&7)  (32 KB)
  __shared__ u16 xsb[64][32];     // [row][k-in-step], kg' = kg ^ ((row>>1)&3)  (4 KB)
  const int t = threadIdx.x;
  const int w = t >> 6, l = t & 63;
  const int rowBase = blockIdx.x * 64;

  {
    const uint4* src = (const uint4*)wsTg;
    uint4* dst = (uint4*)&wsT[0][0];
#pragma unroll
    for (int i = 0; i < 8; ++i) dst[t * 8 + i] = src[t * 8 + i];
  }

  f32x4 acc[4][2];
#pragma unroll
  for (int r = 0; r < 4; ++r)
#pragma unroll
    for (int cf = 0; cf < 2; ++cf) acc[r][cf] = (f32x4){0.f, 0.f, 0.f, 0.f};

  const int rr = t >> 2, cg = t & 3;
  const int grow_s = rowBase + rr;

  for (int kk0 = 0; kk0 < 128; kk0 += 32) {
    float4 v0 = make_float4(0.f, 0.f, 0.f, 0.f), v1 = v0;
    if (grow_s < NN) {
      v0 = *(const float4*)(&x[(size_t)grow_s * 128 + kk0 + cg * 8]);
      v1 = *(const float4*)(&x[(size_t)grow_s * 128 + kk0 + cg * 8 + 4]);
    }
    if (kk0) __syncthreads();
    {
      u32 p0 = bf16pair(v0.x, v0.y);
      u32 p1 = bf16pair(v0.z, v0.w);
      u32 p2 = bf16pair(v1.x, v1.y);
      u32 p3 = bf16pair(v1.z, v1.w);
      int sg = cg ^ ((rr >> 1) & 3);
      *(uint4*)(&xsb[rr][sg * 8]) = make_uint4(p0, p1, p2, p3);
    }
    __syncthreads();

    bf16x8 bfr[2];
#pragma unroll
    for (int cf = 0; cf < 2; ++cf) {
      int col = w * 32 + cf * 16 + (l & 15);
      int kg = (kk0 >> 3) + (l >> 4);
      bfr[cf] = *(const bf16x8*)(&wsT[col][(kg ^ (col & 7)) * 8]);
    }
#pragma unroll
    for (int r = 0; r < 4; ++r) {
      int row = r * 16 + (l & 15);
      int kg = l >> 4;
      bf16x8 afr = *(const bf16x8*)(&xsb[row][(kg ^ ((row >> 1) & 3)) * 8]);
#pragma unroll
      for (int cf = 0; cf < 2; ++cf)
        acc[r][cf] = __builtin_amdgcn_mfma_f32_16x16x32_bf16(afr, bfr[cf], acc[r][cf], 0, 0, 0);
    }
  }

  const int cl = l & 15;
  const int rq = l >> 4;
#pragma unroll
  for (int cf = 0; cf < 2; ++cf) {
    const int h = w * 2 + cf;
    const int gcol = w * 32 + cf * 16 + cl;
    const float as = a1[h * 32 + cl];
    const float ad = a1[h * 32 + 16 + cl];
#pragma unroll
    for (int r = 0; r < 4; ++r) {
#pragma unroll
      for (int i = 0; i < 4; ++i) {
        int grow = rowBase + r * 16 + rq * 4 + i;
        float wh = acc[r][cf][i];
        float ps = wh * as, pd = wh * ad;
        ps += __shfl_xor(ps, 1); ps += __shfl_xor(ps, 2);
        ps += __shfl_xor(ps, 4); ps += __shfl_xor(ps, 8);
        pd += __shfl_xor(pd, 1); pd += __shfl_xor(pd, 2);
        pd += __shfl_xor(pd, 4); pd += __shfl_xor(pd, 8);
        if (grow < NN) {
          Wh1b[(size_t)grow * 128 + gcol] = bf16rte(wh);
          if (cl == 0) { es1[grow * 8 + h] = ps; ed1[grow * 8 + h] = pd; }
        }
      }
    }
  }
}

// ---- Pass B: binning, 2-way replicated counters, DIRECT global scatter ----
__global__ __launch_bounds__(256) void k_bin(
    const int* __restrict__ src, const int* __restrict__ dst,
    int* __restrict__ cur, u32* __restrict__ ebuf)
{
  __shared__ int lcnt2[2][512];
  __shared__ int scn[512];
  __shared__ int goff[NBUCK];
  const int t = threadIdx.x;
  const int wp = (t >> 7) & 1;
  const int e0 = blockIdx.x * 4096;

  lcnt2[0][t] = 0; lcnt2[0][t + 256] = 0;
  lcnt2[1][t] = 0; lcnt2[1][t + 256] = 0;
  __syncthreads();

  u32 ent[16]; short bb[16], lp[16];
#pragma unroll
  for (int i = 0; i < 16; ++i) {
    int e = e0 + i * 256 + t;
    if (e < NE) {
      int s = src[e], d = dst[e];
      int b = d >> BSH;
      ent[i] = (u32)s | ((u32)(d & 255) << 20);
      bb[i] = (short)b;
      lp[i] = (short)atomicAdd(&lcnt2[wp][b], 1);
    } else bb[i] = -1;
  }
  __syncthreads();
  scn[t] = lcnt2[0][t] + lcnt2[1][t];
  scn[t + 256] = lcnt2[0][t + 256] + lcnt2[1][t + 256];
  __syncthreads();
  for (int d = 1; d < 512; d <<= 1) {
    int v0 = (t >= d) ? scn[t - d] : 0;
    int v1 = (t + 256 >= d) ? scn[t + 256 - d] : 0;
    __syncthreads();
    scn[t] += v0; scn[t + 256] += v1;
    __syncthreads();
  }
  for (int b = t; b < NBUCK; b += 256) {
    int excl = b ? scn[b - 1] : 0;
    int cnt = scn[b] - excl;
    if (cnt) goff[b] = b * BCAP + atomicAdd(&cur[b], cnt);
  }
  __syncthreads();
#pragma unroll
  for (int i = 0; i < 16; ++i) {
    if (bb[i] >= 0) {
      int b = bb[i];
      int g = goff[b] + (wp ? lcnt2[0][b] : 0) + lp[i];
      if (g < (b + 1) * BCAP) ebuf[g] = ent[i];
    }
  }
}

// ---------------- Pass C: per-bucket local counting sort ----------------
__global__ __launch_bounds__(256) void k_sort(
    const int* __restrict__ cur, u32* __restrict__ ebuf,
    int* __restrict__ offs, int* __restrict__ deg)
{
  __shared__ u32 ein[BCAP];
  __shared__ u32 eout[BCAP];
  __shared__ int nd[256];
  __shared__ int ncur[256];
  const int t = threadIdx.x;
  const int b = blockIdx.x;
  const int base = b * BCAP;
  int cnt = cur[b];
  if (cnt > BCAP) cnt = BCAP;
  const int nloc = min(256, NN - (b << BSH));

  for (int i = t; i < cnt; i += 256) ein[i] = ebuf[base + i];
  nd[t] = 0;
  __syncthreads();
  for (int i = t; i < cnt; i += 256) atomicAdd(&nd[ein[i] >> 20], 1);
  __syncthreads();
  const int myCnt = nd[t];
  for (int d = 1; d < 256; d <<= 1) {
    int v = (t >= d) ? nd[t - d] : 0;
    __syncthreads();
    nd[t] += v;
    __syncthreads();
  }
  const int excl = t ? nd[t - 1] : 0;
  ncur[t] = excl;
  if (t < nloc) {
    int node = (b << BSH) + t;
    offs[node] = base + excl;
    deg[node]  = myCnt;
  }
  __syncthreads();
  for (int i = t; i < cnt; i += 256) {
    u32 v = ein[i];
    int pos = atomicAdd(&ncur[v >> 20], 1);
    eout[pos] = v & 0xFFFFFu;
  }
  __syncthreads();
  for (int i = t; i < cnt; i += 256) ebuf[base + i] = eout[i];
}

// ---- Layer-1 aggregation FUSED with layer-2 GEMM: 4-deep MLP gather + in-register
//      h1 (never materialized) -> Wh2b (bf16, stride 48) + es2/ed2 ----
__global__ __launch_bounds__(256) void k_agg1g2(
    const u16* __restrict__ Wh1b, const float* __restrict__ es1, const float* __restrict__ ed1,
    const int* __restrict__ offs, const int* __restrict__ deg, const int* __restrict__ csr,
    const u32* __restrict__ wsW2, const float* __restrict__ a2,
    u16* __restrict__ Wh2b, float* __restrict__ es2, float* __restrict__ ed2)
{
  __shared__ u32 W2s[2560];   // [pc 0..19][d 0..127] bf16 pairs (10 KB)
  const int t = threadIdx.x;
#pragma unroll
  for (int i = 0; i < 10; ++i) W2s[t * 10 + i] = wsW2[t * 10 + i];
  __syncthreads();

  const int wid = t >> 6;
  const int lane = t & 63;
  const int n = blockIdx.x * 4 + wid;
  if (n >= NN) return;
  const int s0 = offs[n];
  const int nE = deg[n];
  const int g = lane >> 4;        // edge group 0..3
  const int db = lane & 15;       // dim block
  const int h = db >> 1;          // head
  const float edv = ed1[n * 8 + h];

  f32x2 acc[4];
#pragma unroll
  for (int i = 0; i < 4; ++i) { acc[i].x = 0.f; acc[i].y = 0.f; }
  float ssum = 0.f;

  int c0 = 0;
  for (; c0 + 16 <= nE; c0 += 16) {
    int ss[4];
#pragma unroll
    for (int q = 0; q < 4; ++q) ss[q] = csr[s0 + c0 + q * 4 + g];
    float zz[4];
#pragma unroll
    for (int q = 0; q < 4; ++q) {
      float z = es1[ss[q] * 8 + h] + edv;
      zz[q] = (z > 0.f) ? z : 0.2f * z;
    }
    uint4 raw[4];
#pragma unroll
    for (int q = 0; q < 4; ++q)
      raw[q] = *(const uint4*)(Wh1b + (size_t)ss[q] * 128 + db * 8);
#pragma unroll
    for (int q = 0; q < 4; ++q) {
      const float ww = __expf(zz[q]);
      ssum += ww;
      f32x2 w2; w2.x = ww; w2.y = ww;
      pkfma(acc[0], w2, raw[q].x);
      pkfma(acc[1], w2, raw[q].y);
      pkfma(acc[2], w2, raw[q].z);
      pkfma(acc[3], w2, raw[q].w);
    }
  }
  if (c0 < nE) {
    int jj[4], ss[4];
#pragma unroll
    for (int q = 0; q < 4; ++q) {
      jj[q] = c0 + q * 4 + g;
      ss[q] = csr[s0 + (jj[q] < nE ? jj[q] : 0)];
    }
    float zz[4];
#pragma unroll
    for (int q = 0; q < 4; ++q) {
      float z = es1[ss[q] * 8 + h] + edv;
      zz[q] = (z > 0.f) ? z : 0.2f * z;
    }
#pragma unroll
    for (int q = 0; q < 4; ++q) {
      if (jj[q] < nE) {
        const uint4 raw = *(const uint4*)(Wh1b + (size_t)ss[q] * 128 + db * 8);
        const float ww = __expf(zz[q]);
        ssum += ww;
        f32x2 w2; w2.x = ww; w2.y = ww;
        pkfma(acc[0], w2, raw.x);
        pkfma(acc[1], w2, raw.y);
        pkfma(acc[2], w2, raw.z);
        pkfma(acc[3], w2, raw.w);
      }
    }
  }
  // butterfly: ALL lanes end with the full edge-group sums for their db slice
#pragma unroll
  for (int i = 0; i < 4; ++i) {
    acc[i].x += __shfl_xor(acc[i].x, 16);
    acc[i].y += __shfl_xor(acc[i].y, 16);
    acc[i].x += __shfl_xor(acc[i].x, 32);
    acc[i].y += __shfl_xor(acc[i].y, 32);
  }
  ssum += __shfl_xor(ssum, 16);
  ssum += __shfl_xor(ssum, 32);

  // h1 slice in-register (softmax normalize + ELU), replicated across the 4 groups
  const float inv = 1.f / (ssum + 1e-16f);
  float hv[8];
#pragma unroll
  for (int i = 0; i < 4; ++i) {
    float v0 = acc[i].x * inv;
    float v1 = acc[i].y * inv;
    hv[2 * i]     = (v0 > 0.f) ? v0 : expm1f(v0);
    hv[2 * i + 1] = (v1 > 0.f) ? v1 : expm1f(v1);
  }

  // layer-2 GEMM: group g computes cols g*10..g*10+9; lane covers d = db*8..db*8+7
  float o[10];
#pragma unroll
  for (int j = 0; j < 10; ++j) o[j] = 0.f;
#pragma unroll
  for (int d = 0; d < 8; ++d) {
    const float hvd = hv[d];
    const int row = db * 8 + d;
#pragma unroll
    for (int p = 0; p < 5; ++p) {
      u32 pr = W2s[(g * 5 + p) * 128 + row];
      o[2 * p]     = fmaf(hvd, bflo(pr), o[2 * p]);
      o[2 * p + 1] = fmaf(hvd, bfhi(pr), o[2 * p + 1]);
    }
  }
  // reduce over the 16 db slices (within group)
#pragma unroll
  for (int j = 0; j < 10; ++j) {
    o[j] += __shfl_xor(o[j], 1);
    o[j] += __shfl_xor(o[j], 2);
    o[j] += __shfl_xor(o[j], 4);
    o[j] += __shfl_xor(o[j], 8);
  }
  if (db == 0) {    // lanes 0,16,32,48: each holds 10 final Wh2 cols
    u32* dst = (u32*)(Wh2b + (size_t)n * 48 + g * 10);
    dst[0] = bf16pair(o[0], o[1]);
    dst[1] = bf16pair(o[2], o[3]);
    dst[2] = bf16pair(o[4], o[5]);
    dst[3] = bf16pair(o[6], o[7]);
    dst[4] = bf16pair(o[8], o[9]);
    float pes = 0.f, ped = 0.f;
#pragma unroll
    for (int j = 0; j < 10; ++j) {
      pes = fmaf(o[j], a2[g * 10 + j], pes);
      ped = fmaf(o[j], a2[40 + g * 10 + j], ped);
    }
    pes += __shfl_xor(pes, 16); pes += __shfl_xor(pes, 32);
    ped += __shfl_xor(ped, 16); ped += __shfl_xor(ped, 32);
    if (lane == 0) { es2[n] = pes; ed2[n] = ped; }
  }
}

// ---------------- Layer-2 aggregation: 6 edge-groups x 10 dim-lanes, h2 out bf16 ----------
__global__ __launch_bounds__(256, 8) void k_agg2(
    const u16* __restrict__ Wh2b, const float* __restrict__ es2, const float* __restrict__ ed2,
    const int* __restrict__ offs, const int* __restrict__ deg, const int* __restrict__ csr,
    u32* __restrict__ h2b)
{
  __shared__ float red[4][64][5];
  const int wid = threadIdx.x >> 6;
  const int lane = threadIdx.x & 63;
  const int n = blockIdx.x * 4 + wid;
  if (n >= NN) return;
  const int s0 = offs[n];
  const int nE = deg[n];
  const float edv = ed2[n];
  int e6 = lane / 10;
  const int r10 = lane - e6 * 10;
  const bool act = lane < 60;
  if (e6 > 5) e6 = 5;

  f32x2 acc0, acc1;
  acc0.x = acc0.y = acc1.x = acc1.y = 0.f;
  float ssum = 0.f;

  for (int c0 = 0; c0 < nE; c0 += 24) {
    int jj[4], ss[4];
#pragma unroll
    for (int q = 0; q < 4; ++q) {
      jj[q] = c0 + q * 6 + e6;
      ss[q] = csr[s0 + (jj[q] < nE ? jj[q] : 0)];
    }
    float zz[4];
#pragma unroll
    for (int q = 0; q < 4; ++q) {
      float z = es2[ss[q]] + edv;
      zz[q] = (z > 0.f) ? z : 0.2f * z;
    }
#pragma unroll
    for (int q = 0; q < 4; ++q) {
      if (act && jj[q] < nE) {
        const uint2 raw = *(const uint2*)(Wh2b + (size_t)ss[q] * 48 + r10 * 4);
        const float ww = __expf(zz[q]);
        ssum += ww;
        f32x2 w2; w2.x = ww; w2.y = ww;
        pkfma(acc0, w2, raw.x);
        pkfma(acc1, w2, raw.y);
      }
    }
  }
  red[wid][lane][0] = acc0.x; red[wid][lane][1] = acc0.y;
  red[wid][lane][2] = acc1.x; red[wid][lane][3] = acc1.y;
  red[wid][lane][4] = ssum;
  __builtin_amdgcn_wave_barrier();
  if (lane < 20) {
    const int rb = lane >> 1;
    const int eA = (lane & 1) * 2;
    float aA = 0.f, aB = 0.f, sm = 0.f;
#pragma unroll
    for (int g = 0; g < 6; ++g) {
      aA += red[wid][g * 10 + rb][eA];
      aB += red[wid][g * 10 + rb][eA + 1];
      sm += red[wid][g * 10][4];
    }
    float inv = 1.f / (sm + 1e-16f);
    h2b[(size_t)n * 20 + lane] = bf16pair(aA * inv, aB * inv);
  }
}

// ---------------- Pooling (h2 in bf16) ----------------
__global__ __launch_bounds__(256) void k_pool1(
    const u32* __restrict__ h2b, const int* __restrict__ gstart,
    float* __restrict__ partial)
{
  __shared__ float lds[25][10][4];
  const int g = blockIdx.x >> 3;
  const int p = blockIdx.x & 7;
  const int t = threadIdx.x;
  const int s0 = gstart[g], s1 = gstart[g + 1];
  const int len = s1 - s0;
  const int chunk = (len + PB - 1) / PB;
  const int start = s0 + p * chunk;
  const int end = min(start + chunk, s1);
  const int slot = t / 10, q = t - slot * 10;
  float4 acc = make_float4(0.f, 0.f, 0.f, 0.f);
  if (slot < 25) {
    for (int n = start + slot; n < end; n += 25) {
      const uint2 v = *(const uint2*)(&h2b[(size_t)n * 20 + q * 2]);
      acc.x += bflo(v.x); acc.y += bfhi(v.x);
      acc.z += bflo(v.y); acc.w += bfhi(v.y);
    }
    lds[slot][q][0] = acc.x; lds[slot][q][1] = acc.y;
    lds[slot][q][2] = acc.z; lds[slot][q][3] = acc.w;
  }
  __syncthreads();
  if (t < 40) {
    const int qq = t >> 2, e = t & 3;
    float s = 0.f;
#pragma unroll
    for (int sl = 0; sl < 25; ++sl) s += lds[sl][qq][e];
    partial[(size_t)blockIdx.x * 40 + t] = s;
  }
}

__global__ void k_pool2(const float* __restrict__ partial, const int* __restrict__ gstart,
                        float* __restrict__ out)
{
  const int g = blockIdx.x;
  const int d = threadIdx.x;
  if (d >= 40) return;
  float s = 0.f;
#pragma unroll
  for (int p = 0; p < PB; ++p) s += partial[(size_t)(g * PB + p) * 40 + d];
  int cnt = gstart[g + 1] - gstart[g];
  if (cnt < 1) cnt = 1;
  out[g * 40 + d] = s / (float)cnt;
}

extern "C" void kernel_launch(void* const* d_in, const int* in_sizes, int n_in,
                              void* d_out, int out_size, void* d_ws, size_t ws_size,
                              hipStream_t stream)
{
  const float* x   = (const float*)d_in[0];
  const float* W1  = (const float*)d_in[1];
  const float* a1  = (const float*)d_in[2];
  const float* W2  = (const float*)d_in[3];
  const float* a2  = (const float*)d_in[4];
  const int* eidx  = (const int*)d_in[5];
  const int* batch = (const int*)d_in[6];
  float* out = (float*)d_out;

  char* ws = (char*)d_ws;
  u16*   Wh1b = (u16*)(ws + 0);              // 25,600,000 B (read by agg1g2)
  u32*   h2b  = (u32*)(ws + 9600000);        //  8,000,000 B (reuse of Wh1b region AFTER agg1g2)
  u16*   Wh2b = (u16*)(ws + 25600000);       //  9,600,000 B (old h1b slot; written by agg1g2)
  float* es1  = (float*)(ws + 51200000);     //  3,200,000
  float* ed1  = (float*)(ws + 54400000);     //  3,200,000
  float* es2  = (float*)(ws + 57600000);     //    400,000
  float* ed2  = (float*)(ws + 58000000);     //    400,000
  u32*   ebuf = (u32*)(ws + 58400000);       //  8,007,680 (NBUCK*BCAP*4) -> becomes csr
  int*   offs = (int*)(ws + 66407680);       //    400,000
  int*   deg  = (int*)(ws + 66807680);       //    400,000
  int*   cur  = (int*)(ws + 67207680);       //      2,048
  int*   gstart = (int*)(ws + 67209728);     //        512
  float* partial = (float*)(ws + 67210240);  //     81,920
  u16*   wsTg = (u16*)(ws + 67292160);       //     32,768 (bf16 swizzled W1^T)
  u32*   wsW2 = (u32*)(ws + 67324928);       //     10,240 (bf16 W2 col-pairs)
  // total ~67.3 MB

  const int* esrc = eidx;
  const int* edst = eidx + NE;

  k_prep<<<66, 256, 0, stream>>>(W1, wsTg, batch, gstart, cur, W2, wsW2);
  k_gemm1<<<(NN + 63) / 64, 256, 0, stream>>>(x, wsTg, a1, Wh1b, es1, ed1);
  k_bin<<<(NE + 4095) / 4096, 256, 0, stream>>>(esrc, edst, cur, ebuf);
  k_sort<<<NBUCK, 256, 0, stream>>>(cur, ebuf, offs, deg);
  k_agg1g2<<<(NN + 3) / 4, 256, 0, stream>>>(Wh1b, es1, ed1, offs, deg, (const int*)ebuf,
                                             wsW2, a2, Wh2b, es2, ed2);
  k_agg2<<<(NN + 3) / 4, 256, 0, stream>>>(Wh2b, es2, ed2, offs, deg, (const int*)ebuf, h2b);
  k_pool1<<<NG * PB, 256, 0, stream>>>(h2b, gstart, partial);
  k_pool2<<<NG, 64, 0, stream>>>(partial, gstart, out);
}